// Round 13
// baseline (141.986 us; speedup 1.0000x reference)
//
#include <hip/hip_runtime.h>
#include <math.h>

// B=8, T=2048, D=128, NH=4, HD=32. BT=16384 rows.
// Round 13: r12 (locked, 139.9us) + attn cross-tile pipeline:
//   tri-buffered LDS (tiles kt,kt+1,kt+2), one barrier/tile;
//   QK^T(kt+1) [MFMA, no dep] issued before softmax(kt) [VALU] + PV(kt),
//   so exp2 latency retires under next tile's MFMA issue.
// Everything outside attn_kernel is byte-identical to round 12.

#define T_  2048

typedef short bf16x8 __attribute__((ext_vector_type(8)));
typedef float f32x4  __attribute__((ext_vector_type(4)));
typedef unsigned short ushort_t;

__device__ __forceinline__ float sigm(float x) { return 1.0f / (1.0f + __expf(-x)); }

__device__ __forceinline__ unsigned short f2bf(float x) {
    union { float f; unsigned u; } v; v.f = x;
    unsigned r = v.u + 0x7FFFu + ((v.u >> 16) & 1u);  // RNE
    return (unsigned short)(r >> 16);
}
__device__ __forceinline__ float bf2f(ushort_t u) {
    union { unsigned u; float f; } v; v.u = ((unsigned)u) << 16; return v.f;
}

__device__ __forceinline__ float gelu_f(float x) {
    const float e = exp2f(fmaf(0.044715f * x, x * x, x) * -2.3022083f);
    return x * __builtin_amdgcn_rcpf(1.0f + e);
}
__device__ __forceinline__ float tanh_f(float y) {
    const float e = exp2f(y * 2.8853900818f);
    return 1.0f - 2.0f * __builtin_amdgcn_rcpf(e + 1.0f);
}
#define MX3(a, b, c) fmaxf(fmaxf((a), (b)), (c))

// ---------------- prep: f32 -> bf16 for inputs + all weights -----------------
__global__ __launch_bounds__(256) void prep_kernel(
    const float* __restrict__ lob, const float* __restrict__ trade,
    const float* __restrict__ eiw, const float* __restrict__ ipw,
    const float* __restrict__ opw, const float* __restrict__ lobw,
    const float* __restrict__ trw, const float* __restrict__ ofw,
    ushort_t* __restrict__ pool)
{
    const size_t i8 = ((size_t)blockIdx.x * 256 + threadIdx.x) * 8;
    const float* src; size_t off;
    if      (i8 < 2097152) { src = lob;   off = 0; }
    else if (i8 < 4194304) { src = trade; off = 2097152; }
    else if (i8 < 4210688) { src = eiw;   off = 4194304; }
    else if (i8 < 4259840) { src = ipw;   off = 4210688; }
    else if (i8 < 4276224) { src = opw;   off = 4259840; }
    else if (i8 < 4308992) { src = lobw;  off = 4276224; }
    else if (i8 < 4341760) { src = trw;   off = 4308992; }
    else                   { src = ofw;   off = 4341760; }
    const float4 a = *(const float4*)(src + (i8 - off));
    const float4 b = *(const float4*)(src + (i8 - off) + 4);
    bf16x8 o;
    o[0] = (short)f2bf(a.x); o[1] = (short)f2bf(a.y);
    o[2] = (short)f2bf(a.z); o[3] = (short)f2bf(a.w);
    o[4] = (short)f2bf(b.x); o[5] = (short)f2bf(b.y);
    o[6] = (short)f2bf(b.z); o[7] = (short)f2bf(b.w);
    *(bf16x8*)(pool + i8) = o;
}

// ---------------- ei GEMM + LN + tanh*extra -> bf16 impact -------------------
__global__ __launch_bounds__(256) void gemm_ei(
    const ushort_t* __restrict__ Xb0, const ushort_t* __restrict__ Wb,
    const float* __restrict__ bias, const float* __restrict__ gamma,
    const float* __restrict__ beta, const float* __restrict__ extra,
    ushort_t* __restrict__ outb)
{
    __shared__ float red[32][2][2];
    const int tid = threadIdx.x, wid = tid >> 6, lane = tid & 63;
    const int c2 = lane & 15, g = lane >> 4;
    const int rowblk = wid >> 1, chf = wid & 1, cb0 = chf * 4;
    const int R0 = blockIdx.x * 32 + rowblk * 16;

    f32x4 acc[4] = {};
#pragma unroll
    for (int ch = 0; ch < 4; ch++) {
        const bf16x8 a = *(const bf16x8*)(Xb0 + (size_t)(R0 + c2) * 128 + ch * 32 + g * 8);
#pragma unroll
        for (int j = 0; j < 4; j++) {
            const bf16x8 b = *(const bf16x8*)(Wb + (size_t)((cb0 + j) * 16 + c2) * 128 + ch * 32 + g * 8);
            acc[j] = __builtin_amdgcn_mfma_f32_16x16x32_bf16(a, b, acc[j], 0, 0, 0);
        }
    }
    float gm[4], bt[4];
#pragma unroll
    for (int j = 0; j < 4; j++) {
        const int col = (cb0 + j) * 16 + c2;
        const float bb = bias[col];
        gm[j] = gamma[col]; bt[j] = beta[col];
#pragma unroll
        for (int r = 0; r < 4; r++) acc[j][r] += bb;
    }
#pragma unroll
    for (int r = 0; r < 4; r++) {
        float s = 0.f, ss = 0.f;
#pragma unroll
        for (int j = 0; j < 4; j++) { const float v = acc[j][r]; s += v; ss = fmaf(v, v, ss); }
#pragma unroll
        for (int o = 8; o; o >>= 1) { s += __shfl_xor(s, o); ss += __shfl_xor(ss, o); }
        if (c2 == 0) {
            red[rowblk * 16 + 4 * g + r][chf][0] = s;
            red[rowblk * 16 + 4 * g + r][chf][1] = ss;
        }
    }
    __syncthreads();
#pragma unroll
    for (int r = 0; r < 4; r++) {
        const int lr = rowblk * 16 + 4 * g + r;
        const float S  = red[lr][0][0] + red[lr][1][0];
        const float SS = red[lr][0][1] + red[lr][1][1];
        const float mean = S * (1.0f / 128.0f);
        float var = SS * (1.0f / 128.0f) - mean * mean;
        var = fmaxf(var, 0.0f);
        const float rstd = rsqrtf(var + 1e-5f);
        const int R = blockIdx.x * 32 + lr;
        const float ext = extra[R];
#pragma unroll
        for (int j = 0; j < 4; j++) {
            const float y = (acc[j][r] - mean) * rstd * gm[j] + bt[j];
            outb[(size_t)R * 128 + (cb0 + j) * 16 + c2] = f2bf(tanh_f(y) * ext);
        }
    }
}

// ---------------- fused enh (lobe+tre) + qkv ---------------------------------
__global__ __launch_bounds__(256) void enh_qkv(
    const ushort_t* __restrict__ lobb, const ushort_t* __restrict__ trab,
    const ushort_t* __restrict__ stab,
    const ushort_t* __restrict__ lobw, const ushort_t* __restrict__ trw,
    const ushort_t* __restrict__ ipw, const float* __restrict__ ipb,
    const float* __restrict__ lob_b, const float* __restrict__ lob_g,
    const float* __restrict__ lob_beta,
    const float* __restrict__ tr_b, const float* __restrict__ tr_g,
    const float* __restrict__ tr_beta,
    ushort_t* __restrict__ lobe_b, ushort_t* __restrict__ tre_bf,
    ushort_t* __restrict__ qo, ushort_t* __restrict__ ko, ushort_t* __restrict__ vo)
{
    __shared__ ushort_t lob_t[32][136];
    __shared__ ushort_t tre_t[32][136];
    __shared__ ushort_t vls[128][36];
    __shared__ float red[32][2][4];
    const int tid = threadIdx.x, wid = tid >> 6, lane = tid & 63;
    const int c2 = lane & 15, g = lane >> 4;
    const int rowblk = wid >> 1, chf = wid & 1, cb0 = chf * 4;
    const int RB = blockIdx.x * 32;
    const int R0 = RB + rowblk * 16;

    f32x4 aL[4] = {}, aT[4] = {};
#pragma unroll
    for (int ch = 0; ch < 8; ch++) {
        const int kk = (ch & 3) * 32;
        bf16x8 xl, xt;
        if (ch < 4) {
            xl = *(const bf16x8*)(lobb + (size_t)(R0 + c2) * 128 + kk + g * 8);
            xt = *(const bf16x8*)(trab + (size_t)(R0 + c2) * 128 + kk + g * 8);
        } else {
            xl = *(const bf16x8*)(stab + (size_t)(R0 + c2) * 128 + kk + g * 8);
            xt = xl;
        }
#pragma unroll
        for (int j = 0; j < 4; j++) {
            const size_t wo = (size_t)((cb0 + j) * 16 + c2) * 256 + ch * 32 + g * 8;
            aL[j] = __builtin_amdgcn_mfma_f32_16x16x32_bf16(xl, *(const bf16x8*)(lobw + wo), aL[j], 0, 0, 0);
            aT[j] = __builtin_amdgcn_mfma_f32_16x16x32_bf16(xt, *(const bf16x8*)(trw + wo), aT[j], 0, 0, 0);
        }
    }
#pragma unroll
    for (int j = 0; j < 4; j++) {
        const int col = (cb0 + j) * 16 + c2;
        const float bL = lob_b[col], bT = tr_b[col];
#pragma unroll
        for (int r = 0; r < 4; r++) { aL[j][r] += bL; aT[j][r] += bT; }
    }
#pragma unroll
    for (int r = 0; r < 4; r++) {
        float sL = 0.f, ssL = 0.f, sT = 0.f, ssT = 0.f;
#pragma unroll
        for (int j = 0; j < 4; j++) {
            const float vL = aL[j][r], vT = aT[j][r];
            sL += vL; ssL = fmaf(vL, vL, ssL);
            sT += vT; ssT = fmaf(vT, vT, ssT);
        }
#pragma unroll
        for (int o = 8; o; o >>= 1) {
            sL += __shfl_xor(sL, o); ssL += __shfl_xor(ssL, o);
            sT += __shfl_xor(sT, o); ssT += __shfl_xor(ssT, o);
        }
        if (c2 == 0) {
            float* rd = red[rowblk * 16 + 4 * g + r][chf];
            rd[0] = sL; rd[1] = ssL; rd[2] = sT; rd[3] = ssT;
        }
    }
    __syncthreads();
#pragma unroll
    for (int r = 0; r < 4; r++) {
        const int lr = rowblk * 16 + 4 * g + r;
        const int R = RB + lr;
        const float SL  = red[lr][0][0] + red[lr][1][0];
        const float SSL = red[lr][0][1] + red[lr][1][1];
        const float ST  = red[lr][0][2] + red[lr][1][2];
        const float SST = red[lr][0][3] + red[lr][1][3];
        const float mL = SL * (1.0f / 128.0f), mT = ST * (1.0f / 128.0f);
        const float rL = rsqrtf(fmaxf(SSL * (1.0f / 128.0f) - mL * mL, 0.0f) + 1e-5f);
        const float rT = rsqrtf(fmaxf(SST * (1.0f / 128.0f) - mT * mT, 0.0f) + 1e-5f);
#pragma unroll
        for (int j = 0; j < 4; j++) {
            const int col = (cb0 + j) * 16 + c2;
            const float yL = gelu_f((aL[j][r] - mL) * rL * lob_g[col] + lob_beta[col]);
            const float yT = gelu_f((aT[j][r] - mT) * rT * tr_g[col] + tr_beta[col]);
            const ushort_t lb = f2bf(yL);
            lobe_b[(size_t)R * 128 + col] = lb;
            lob_t[lr][col] = lb;
            const ushort_t tb = f2bf(yT);
            tre_bf[(size_t)R * 128 + col] = tb;
            tre_t[lr][col] = tb;
        }
    }
    __syncthreads();

    const float qscale = 0.17677669529663687f * 1.4426950408889634f;
#pragma unroll
    for (int which = 0; which < 3; which++) {
        const ushort_t (*src)[136] = (which == 0) ? lob_t : tre_t;
        const ushort_t* Wp = ipw + (size_t)which * 16384;
        f32x4 pa[4] = {};
#pragma unroll
        for (int ch = 0; ch < 4; ch++) {
            const bf16x8 a = *(const bf16x8*)&src[rowblk * 16 + c2][ch * 32 + g * 8];
#pragma unroll
            for (int j = 0; j < 4; j++) {
                const bf16x8 b = *(const bf16x8*)(Wp + (size_t)((cb0 + j) * 16 + c2) * 128 + ch * 32 + g * 8);
                pa[j] = __builtin_amdgcn_mfma_f32_16x16x32_bf16(a, b, pa[j], 0, 0, 0);
            }
        }
        if (which < 2) {
            ushort_t* dst = (which == 0) ? qo : ko;
            const float sc = (which == 0) ? qscale : 1.0f;
#pragma unroll
            for (int j = 0; j < 4; j++) {
                const int col = (cb0 + j) * 16 + c2;
                const float bb = ipb[which * 128 + col];
                const int h = col >> 5, hd = col & 31;
#pragma unroll
                for (int r = 0; r < 4; r++) {
                    const int R = R0 + 4 * g + r;
                    const int b = R >> 11, t = R & 2047;
                    dst[(((size_t)b * 4 + h) * 2048 + t) * 32 + hd] = f2bf((pa[j][r] + bb) * sc);
                }
            }
        } else {
#pragma unroll
            for (int j = 0; j < 4; j++) {
                const int col = (cb0 + j) * 16 + c2;
                const float bb = ipb[256 + col];
#pragma unroll
                for (int r = 0; r < 4; r++)
                    vls[col][rowblk * 16 + 4 * g + r] = f2bf(pa[j][r] + bb);
            }
        }
    }
    __syncthreads();
    // V^T global write with kappa permutation (PV B-frag = lane's own words)
    {
        const int col = tid >> 1, hf = tid & 1;
        const int h = col >> 5, hd = col & 31;
        const int b = RB >> 11;
        unsigned w[8];
#pragma unroll
        for (int e = 0; e < 8; e++) {
            const int p0 = hf * 16 + 2 * e;
            const int g2 = p0 >> 3, j2 = p0 & 7;
            const int lk = 4 * g2 + j2 + (j2 >= 4 ? 12 : 0);
            w[e] = (unsigned)vls[col][lk] | ((unsigned)vls[col][lk + 1] << 16);
        }
        ushort_t* dst = vo + (((size_t)b * 4 + h) * 32 + hd) * 2048 + (RB & 2047) + hf * 16;
        *(uint4*)dst       = *(const uint4*)&w[0];
        *(uint4*)(dst + 8) = *(const uint4*)&w[4];
    }
}

// ------ flash attention: split-K x2, tri-buffer cross-tile pipeline ----------
__global__ __launch_bounds__(256) void attn_kernel(
    const ushort_t* __restrict__ q, const ushort_t* __restrict__ k,
    const ushort_t* __restrict__ vtg,
    ushort_t* __restrict__ part, float* __restrict__ rs_part,
    float* __restrict__ m_part)
{
    __shared__ ushort_t ks[3][64][40];   // K tiles  [buf][key][hd]
    __shared__ ushort_t vt[3][32][72];   // V^T tiles[buf][d][kappa-pos]
    const int tid = threadIdx.x, wid = tid >> 6, lane = tid & 63;
    const int c = lane & 15, g = lane >> 4;
    const int half = blockIdx.x & 1, qt = blockIdx.x >> 1;
    const int bh = blockIdx.y, b = bh >> 2, h = bh & 3;
    const ushort_t* kb_ = k   + (size_t)bh * 65536 + (size_t)half * 1024 * 32;
    const ushort_t* vb_ = vtg + (size_t)bh * 65536 + (size_t)half * 1024;
    const int q0 = qt * 128 + wid * 32;

    const ushort_t* qbase = q + ((size_t)bh * 2048 + q0) * 32;
    const bf16x8 qf0 = *(const bf16x8*)(qbase + (size_t)c * 32 + g * 8);
    const bf16x8 qf1 = *(const bf16x8*)(qbase + (size_t)(16 + c) * 32 + g * 8);

    bf16x8 ones;
#pragma unroll
    for (int i = 0; i < 8; i++) ones[i] = (short)0x3F80;

    float m0 = 0.0f, m1 = 0.0f;
    f32x4 acc[2][2] = {};
    f32x4 racc[2] = {};

    const int srow = tid >> 2, ssg = tid & 3;  // K staging
    const int vd = tid >> 3, vkg = tid & 7;    // V^T staging

    // prologue: stage tiles 0 and 1
    {
        const bf16x8 k0 = *(const bf16x8*)(kb_ + (size_t)srow * 32 + ssg * 8);
        const bf16x8 v0 = *(const bf16x8*)(vb_ + (size_t)vd * 2048 + vkg * 8);
        *(bf16x8*)&ks[0][srow][ssg * 8] = k0;
        *(bf16x8*)&vt[0][vd][vkg * 8] = v0;
        const bf16x8 k1 = *(const bf16x8*)(kb_ + ((size_t)64 + srow) * 32 + ssg * 8);
        const bf16x8 v1 = *(const bf16x8*)(vb_ + (size_t)vd * 2048 + 64 + vkg * 8);
        *(bf16x8*)&ks[1][srow][ssg * 8] = k1;
        *(bf16x8*)&vt[1][vd][vkg * 8] = v1;
    }
    __syncthreads();

    // QK^T of a tile (swapped operands): both q-frags
    auto qk_compute = [&](int buf, f32x4 (&t0)[4], f32x4 (&t1)[4]) {
        __builtin_amdgcn_s_setprio(1);
#pragma unroll
        for (int kb2 = 0; kb2 < 4; kb2++) {
            const bf16x8 kf = *(const bf16x8*)&ks[buf][kb2 * 16 + c][g * 8];
            f32x4 z = {};
            t0[kb2] = __builtin_amdgcn_mfma_f32_16x16x32_bf16(kf, qf0, z, 0, 0, 0);
            t1[kb2] = __builtin_amdgcn_mfma_f32_16x16x32_bf16(kf, qf1, z, 0, 0, 0);
        }
        __builtin_amdgcn_s_setprio(0);
    };

    f32x4 sA0[4], sA1[4], sB0[4], sB1[4];
    qk_compute(0, sA0, sA1);   // tile 0 scores

    int bufC = 0, bufN = 1, bufW = 2;  // tiles kt, kt+1, (kt+2 dest)

    auto iter = [&](int kt, f32x4 (&sC0)[4], f32x4 (&sC1)[4],
                            f32x4 (&sN0)[4], f32x4 (&sN1)[4]) {
        // 1. issue global loads for tile kt+2
        bf16x8 kk8, vv8;
        const bool pf = (kt + 2 < 16);
        if (pf) {
            kk8 = *(const bf16x8*)(kb_ + ((size_t)(kt + 2) * 64 + srow) * 32 + ssg * 8);
            vv8 = *(const bf16x8*)(vb_ + (size_t)vd * 2048 + (kt + 2) * 64 + vkg * 8);
        }
        // 2. QK^T of tile kt+1 (independent of softmax below -> overlap)
        if (kt + 1 < 16) qk_compute(bufN, sN0, sN1);

        // 3. softmax on current tile's scores (guard: max3 triples)
        float lm = MX3(sC0[0][0], sC0[0][1], sC0[0][2]);
        lm = MX3(lm, sC0[0][3], sC0[1][0]);
        lm = MX3(lm, sC0[1][1], sC0[1][2]);
        lm = MX3(lm, sC0[1][3], sC0[2][0]);
        lm = MX3(lm, sC0[2][1], sC0[2][2]);
        lm = MX3(lm, sC0[2][3], sC0[3][0]);
        lm = MX3(lm, sC0[3][1], sC0[3][2]);
        lm = MX3(lm, sC0[3][3], sC1[0][0]);
        lm = MX3(lm, sC1[0][1], sC1[0][2]);
        lm = MX3(lm, sC1[0][3], sC1[1][0]);
        lm = MX3(lm, sC1[1][1], sC1[1][2]);
        lm = MX3(lm, sC1[1][3], sC1[2][0]);
        lm = MX3(lm, sC1[2][1], sC1[2][2]);
        lm = MX3(lm, sC1[2][3], sC1[3][0]);
        lm = MX3(lm, sC1[3][1], sC1[3][2]);
        lm = fmaxf(lm, sC1[3][3]);
        if (__any(lm > 80.0f || m0 != 0.0f || m1 != 0.0f)) {
            float l0 = -1e30f, l1 = -1e30f;
#pragma unroll
            for (int kb2 = 0; kb2 < 4; kb2++) {
#pragma unroll
                for (int r = 0; r < 4; r++) { l0 = fmaxf(l0, sC0[kb2][r]); l1 = fmaxf(l1, sC1[kb2][r]); }
            }
            l0 = fmaxf(l0, __shfl_xor(l0, 16)); l0 = fmaxf(l0, __shfl_xor(l0, 32));
            l1 = fmaxf(l1, __shfl_xor(l1, 16)); l1 = fmaxf(l1, __shfl_xor(l1, 32));
            const float n0 = fmaxf(m0, l0), n1 = fmaxf(m1, l1);
            const float a0 = exp2f(m0 - n0), a1 = exp2f(m1 - n1);
#pragma unroll
            for (int nb = 0; nb < 2; nb++)
#pragma unroll
                for (int r = 0; r < 4; r++) { acc[0][nb][r] *= a0; acc[1][nb][r] *= a1; }
#pragma unroll
            for (int r = 0; r < 4; r++) { racc[0][r] *= a0; racc[1][r] *= a1; }
            m0 = n0; m1 = n1;
#pragma unroll
            for (int kb2 = 0; kb2 < 4; kb2++)
#pragma unroll
                for (int r = 0; r < 4; r++) {
                    sC0[kb2][r] = exp2f(sC0[kb2][r] - m0);
                    sC1[kb2][r] = exp2f(sC1[kb2][r] - m1);
                }
        } else {
#pragma unroll
            for (int kb2 = 0; kb2 < 4; kb2++)
#pragma unroll
                for (int r = 0; r < 4; r++) {
                    sC0[kb2][r] = exp2f(sC0[kb2][r]);
                    sC1[kb2][r] = exp2f(sC1[kb2][r]);
                }
        }

        // 4. pack P to bf16 (lane-local; kappa layout matches V^T)
        union { unsigned u[4]; bf16x8 v; } p0a, p0b, p1a, p1b;
        asm("v_cvt_pk_bf16_f32 %0, %1, %2" : "=v"(p0a.u[0]) : "v"(sC0[0][0]), "v"(sC0[0][1]));
        asm("v_cvt_pk_bf16_f32 %0, %1, %2" : "=v"(p0a.u[1]) : "v"(sC0[0][2]), "v"(sC0[0][3]));
        asm("v_cvt_pk_bf16_f32 %0, %1, %2" : "=v"(p0a.u[2]) : "v"(sC0[1][0]), "v"(sC0[1][1]));
        asm("v_cvt_pk_bf16_f32 %0, %1, %2" : "=v"(p0a.u[3]) : "v"(sC0[1][2]), "v"(sC0[1][3]));
        asm("v_cvt_pk_bf16_f32 %0, %1, %2" : "=v"(p0b.u[0]) : "v"(sC0[2][0]), "v"(sC0[2][1]));
        asm("v_cvt_pk_bf16_f32 %0, %1, %2" : "=v"(p0b.u[1]) : "v"(sC0[2][2]), "v"(sC0[2][3]));
        asm("v_cvt_pk_bf16_f32 %0, %1, %2" : "=v"(p0b.u[2]) : "v"(sC0[3][0]), "v"(sC0[3][1]));
        asm("v_cvt_pk_bf16_f32 %0, %1, %2" : "=v"(p0b.u[3]) : "v"(sC0[3][2]), "v"(sC0[3][3]));
        asm("v_cvt_pk_bf16_f32 %0, %1, %2" : "=v"(p1a.u[0]) : "v"(sC1[0][0]), "v"(sC1[0][1]));
        asm("v_cvt_pk_bf16_f32 %0, %1, %2" : "=v"(p1a.u[1]) : "v"(sC1[0][2]), "v"(sC1[0][3]));
        asm("v_cvt_pk_bf16_f32 %0, %1, %2" : "=v"(p1a.u[2]) : "v"(sC1[1][0]), "v"(sC1[1][1]));
        asm("v_cvt_pk_bf16_f32 %0, %1, %2" : "=v"(p1a.u[3]) : "v"(sC1[1][2]), "v"(sC1[1][3]));
        asm("v_cvt_pk_bf16_f32 %0, %1, %2" : "=v"(p1b.u[0]) : "v"(sC1[2][0]), "v"(sC1[2][1]));
        asm("v_cvt_pk_bf16_f32 %0, %1, %2" : "=v"(p1b.u[1]) : "v"(sC1[2][2]), "v"(sC1[2][3]));
        asm("v_cvt_pk_bf16_f32 %0, %1, %2" : "=v"(p1b.u[2]) : "v"(sC1[3][0]), "v"(sC1[3][1]));
        asm("v_cvt_pk_bf16_f32 %0, %1, %2" : "=v"(p1b.u[3]) : "v"(sC1[3][2]), "v"(sC1[3][3]));

        // 5. PV + denominator (matrix pipe), V from bufC
        __builtin_amdgcn_s_setprio(1);
#pragma unroll
        for (int nb = 0; nb < 2; nb++) {
            const bf16x8 v0 = *(const bf16x8*)&vt[bufC][nb * 16 + c][g * 8];
            const bf16x8 v1 = *(const bf16x8*)&vt[bufC][nb * 16 + c][32 + g * 8];
            acc[0][nb] = __builtin_amdgcn_mfma_f32_16x16x32_bf16(v0, p0a.v, acc[0][nb], 0, 0, 0);
            acc[0][nb] = __builtin_amdgcn_mfma_f32_16x16x32_bf16(v1, p0b.v, acc[0][nb], 0, 0, 0);
            acc[1][nb] = __builtin_amdgcn_mfma_f32_16x16x32_bf16(v0, p1a.v, acc[1][nb], 0, 0, 0);
            acc[1][nb] = __builtin_amdgcn_mfma_f32_16x16x32_bf16(v1, p1b.v, acc[1][nb], 0, 0, 0);
        }
        racc[0] = __builtin_amdgcn_mfma_f32_16x16x32_bf16(ones, p0a.v, racc[0], 0, 0, 0);
        racc[0] = __builtin_amdgcn_mfma_f32_16x16x32_bf16(ones, p0b.v, racc[0], 0, 0, 0);
        racc[1] = __builtin_amdgcn_mfma_f32_16x16x32_bf16(ones, p1a.v, racc[1], 0, 0, 0);
        racc[1] = __builtin_amdgcn_mfma_f32_16x16x32_bf16(ones, p1b.v, racc[1], 0, 0, 0);
        __builtin_amdgcn_s_setprio(0);

        // 6. write tile kt+2 into bufW (prior content last read before the
        //    barrier that ended iteration kt-1 -> safe)
        if (pf) {
            *(bf16x8*)&ks[bufW][srow][ssg * 8] = kk8;
            *(bf16x8*)&vt[bufW][vd][vkg * 8] = vv8;
        }
        __syncthreads();
        const int t = bufC; bufC = bufN; bufN = bufW; bufW = t;
    };

    for (int kt = 0; kt < 16; kt += 2) {
        iter(kt,     sA0, sA1, sB0, sB1);
        iter(kt + 1, sB0, sB1, sA0, sA1);
    }

    // ---- partial store in ctx layout: part[half][b][t][h*32+d] (uint2) ------
    ushort_t* pb = part + (size_t)half * 2097152;
#pragma unroll
    for (int qf = 0; qf < 2; qf++) {
        const int qrow = q0 + qf * 16 + c;
        ushort_t* dst = pb + ((size_t)(b * 2048 + qrow)) * 128 + h * 32;
#pragma unroll
        for (int nb = 0; nb < 2; nb++) {
            unsigned w0, w1;
            asm("v_cvt_pk_bf16_f32 %0, %1, %2" : "=v"(w0) : "v"(acc[qf][nb][0]), "v"(acc[qf][nb][1]));
            asm("v_cvt_pk_bf16_f32 %0, %1, %2" : "=v"(w1) : "v"(acc[qf][nb][2]), "v"(acc[qf][nb][3]));
            uint2 wv; wv.x = w0; wv.y = w1;
            *(uint2*)(dst + nb * 16 + 4 * g) = wv;
        }
    }
    if (g == 0) {
        float* rsp = rs_part + (size_t)(half * 32 + bh) * 2048;
        float* mp  = m_part  + (size_t)(half * 32 + bh) * 2048;
        rsp[q0 + c]      = racc[0][0];
        rsp[q0 + 16 + c] = racc[1][0];
        mp[q0 + c]       = m0;
        mp[q0 + 16 + c]  = m1;
    }
}

// ------- fused split-K combine + out-proj + residual-LN + final GEMM ---------
__global__ __launch_bounds__(256) void out_fuse(
    const ushort_t* __restrict__ ctxA, const ushort_t* __restrict__ ctxB,
    const float* __restrict__ rs_part, const float* __restrict__ m_part,
    const ushort_t* __restrict__ treb,
    const ushort_t* __restrict__ opw, const float* __restrict__ opb,
    const float* __restrict__ cn_g, const float* __restrict__ cn_b,
    const ushort_t* __restrict__ ofw, const float* __restrict__ of_b,
    const float* __restrict__ of_g, const float* __restrict__ of_beta,
    const ushort_t* __restrict__ lobe_b, float* __restrict__ out)
{
    __shared__ ushort_t fus_t[32][136];
    __shared__ float red[32][2][2];
    const int tid = threadIdx.x, wid = tid >> 6, lane = tid & 63;
    const int c2 = lane & 15, g = lane >> 4;
    const int rowblk = wid >> 1, chf = wid & 1, cb0 = chf * 4;
    const int RB = blockIdx.x * 32;
    const int R0 = RB + rowblk * 16;

    // ---- per-lane-row, per-head combine factors ----
    const int rowA = R0 + c2;
    const int bb2 = rowA >> 11, tt = rowA & 2047;
    float fA[4], fB[4];
#pragma unroll
    for (int h = 0; h < 4; h++) {
        const int bh = bb2 * 4 + h;
        const float mA = m_part[(size_t)bh * 2048 + tt];
        const float mB = m_part[(size_t)(32 + bh) * 2048 + tt];
        const float rA = rs_part[(size_t)bh * 2048 + tt];
        const float rB = rs_part[(size_t)(32 + bh) * 2048 + tt];
        const float M = fmaxf(mA, mB);
        const float wA = exp2f(mA - M), wB = exp2f(mB - M);
        const float inv = __builtin_amdgcn_rcpf(fmaf(rA, wA, rB * wB));
        fA[h] = wA * inv; fB[h] = wB * inv;
    }

    // ---- phase A: fused = LN(lobe + combined_ctx @ opw + opb) ----
    f32x4 acc[4] = {};
#pragma unroll
    for (int ch = 0; ch < 4; ch++) {
        const bf16x8 aA = *(const bf16x8*)(ctxA + (size_t)rowA * 128 + ch * 32 + g * 8);
        const bf16x8 aB = *(const bf16x8*)(ctxB + (size_t)rowA * 128 + ch * 32 + g * 8);
        union { unsigned u[4]; bf16x8 v; } am;
#pragma unroll
        for (int i = 0; i < 4; i++) {
            const float e0 = bf2f((ushort_t)aA[2 * i]) * fA[ch] + bf2f((ushort_t)aB[2 * i]) * fB[ch];
            const float e1 = bf2f((ushort_t)aA[2 * i + 1]) * fA[ch] + bf2f((ushort_t)aB[2 * i + 1]) * fB[ch];
            asm("v_cvt_pk_bf16_f32 %0, %1, %2" : "=v"(am.u[i]) : "v"(e0), "v"(e1));
        }
#pragma unroll
        for (int j = 0; j < 4; j++) {
            const bf16x8 b = *(const bf16x8*)(opw + (size_t)((cb0 + j) * 16 + c2) * 128 + ch * 32 + g * 8);
            acc[j] = __builtin_amdgcn_mfma_f32_16x16x32_bf16(am.v, b, acc[j], 0, 0, 0);
        }
    }
#pragma unroll
    for (int j = 0; j < 4; j++) {
        const int col = (cb0 + j) * 16 + c2;
        const float bb = opb[col];
#pragma unroll
        for (int r = 0; r < 4; r++)
            acc[j][r] += bb + bf2f(lobe_b[(size_t)(R0 + 4 * g + r) * 128 + col]);
    }
#pragma unroll
    for (int r = 0; r < 4; r++) {
        float s = 0.f, ss = 0.f;
#pragma unroll
        for (int j = 0; j < 4; j++) { const float v = acc[j][r]; s += v; ss = fmaf(v, v, ss); }
#pragma unroll
        for (int o = 8; o; o >>= 1) { s += __shfl_xor(s, o); ss += __shfl_xor(ss, o); }
        if (c2 == 0) {
            red[rowblk * 16 + 4 * g + r][chf][0] = s;
            red[rowblk * 16 + 4 * g + r][chf][1] = ss;
        }
    }
    __syncthreads();
#pragma unroll
    for (int r = 0; r < 4; r++) {
        const int lr = rowblk * 16 + 4 * g + r;
        const float S  = red[lr][0][0] + red[lr][1][0];
        const float SS = red[lr][0][1] + red[lr][1][1];
        const float mean = S * (1.0f / 128.0f);
        const float rstd = rsqrtf(fmaxf(SS * (1.0f / 128.0f) - mean * mean, 0.0f) + 1e-5f);
#pragma unroll
        for (int j = 0; j < 4; j++) {
            const int col = (cb0 + j) * 16 + c2;
            fus_t[lr][col] = f2bf((acc[j][r] - mean) * rstd * cn_g[col] + cn_b[col]);
        }
    }
    __syncthreads();

    // ---- phase B: out = gelu(LN([fused, tre]@ofw + ofb)) ----
    f32x4 a2[4] = {};
#pragma unroll
    for (int ch = 0; ch < 8; ch++) {
        bf16x8 a;
        if (ch < 4) a = *(const bf16x8*)&fus_t[rowblk * 16 + c2][ch * 32 + g * 8];
        else        a = *(const bf16x8*)(treb + (size_t)(R0 + c2) * 128 + (ch - 4) * 32 + g * 8);
#pragma unroll
        for (int j = 0; j < 4; j++) {
            const bf16x8 b = *(const bf16x8*)(ofw + (size_t)((cb0 + j) * 16 + c2) * 256 + ch * 32 + g * 8);
            a2[j] = __builtin_amdgcn_mfma_f32_16x16x32_bf16(a, b, a2[j], 0, 0, 0);
        }
    }
#pragma unroll
    for (int j = 0; j < 4; j++) {
        const float bb = of_b[(cb0 + j) * 16 + c2];
#pragma unroll
        for (int r = 0; r < 4; r++) a2[j][r] += bb;
    }
#pragma unroll
    for (int r = 0; r < 4; r++) {
        float s = 0.f, ss = 0.f;
#pragma unroll
        for (int j = 0; j < 4; j++) { const float v = a2[j][r]; s += v; ss = fmaf(v, v, ss); }
#pragma unroll
        for (int o = 8; o; o >>= 1) { s += __shfl_xor(s, o); ss += __shfl_xor(ss, o); }
        if (c2 == 0) {
            red[rowblk * 16 + 4 * g + r][chf][0] = s;
            red[rowblk * 16 + 4 * g + r][chf][1] = ss;
        }
    }
    __syncthreads();
#pragma unroll
    for (int r = 0; r < 4; r++) {
        const int lr = rowblk * 16 + 4 * g + r;
        const float S  = red[lr][0][0] + red[lr][1][0];
        const float SS = red[lr][0][1] + red[lr][1][1];
        const float mean = S * (1.0f / 128.0f);
        const float rstd = rsqrtf(fmaxf(SS * (1.0f / 128.0f) - mean * mean, 0.0f) + 1e-5f);
        const int R = RB + lr;
#pragma unroll
        for (int j = 0; j < 4; j++) {
            const int col = (cb0 + j) * 16 + c2;
            const float y = (a2[j][r] - mean) * rstd * of_g[col] + of_beta[col];
            out[(size_t)R * 128 + col] = gelu_f(y);
        }
    }
}

// ---------------- decay scan: ends -> carry -> re-scan -----------------------
__global__ void scan_ends_kernel(const ushort_t* __restrict__ imp,
                                 const float* __restrict__ decay,
                                 float* __restrict__ ends)
{
    const int c = threadIdx.x;
    const int ch = blockIdx.x, b = blockIdx.y;
    const float d = sigm(decay[c]);
    const size_t base = ((size_t)b * T_ + ch * 64) * 128 + c;
    float s = 0.0f;
#pragma unroll 4
    for (int tl = 0; tl < 64; tl++)
        s = fmaf(d, s, bf2f(imp[base + (size_t)tl * 128]));
    ends[((size_t)b * 32 + ch) * 128 + c] = s;
}

__global__ void scan_carry_kernel(const float* __restrict__ ends,
                                  const float* __restrict__ decay,
                                  float* __restrict__ carry)
{
    const int c = threadIdx.x;
    const int b = blockIdx.x;
    const float d = sigm(decay[c]);
    float dl = d;
#pragma unroll
    for (int i = 0; i < 6; i++) dl *= dl;  // d^64
    float e = 0.0f;
#pragma unroll
    for (int ch = 0; ch < 32; ch++) {
        carry[((size_t)b * 32 + ch) * 128 + c] = e;
        e = fmaf(dl, e, ends[((size_t)b * 32 + ch) * 128 + c]);
    }
}

__global__ void scan_fin_kernel(const ushort_t* __restrict__ imp,
                                const float* __restrict__ decay,
                                const float* __restrict__ carry,
                                ushort_t* __restrict__ stbf)
{
    const int c = threadIdx.x;
    const int ch = blockIdx.x, b = blockIdx.y;
    const float d = sigm(decay[c]);
    float s = carry[((size_t)b * 32 + ch) * 128 + c];
    const size_t base = ((size_t)b * T_ + ch * 64) * 128 + c;
#pragma unroll 4
    for (int tl = 0; tl < 64; tl++) {
        s = fmaf(d, s, bf2f(imp[base + (size_t)tl * 128]));
        stbf[base + (size_t)tl * 128] = f2bf(s);
    }
}

extern "C" void kernel_launch(void* const* d_in, const int* in_sizes, int n_in,
                              void* d_out, int out_size, void* d_ws, size_t ws_size,
                              hipStream_t stream)
{
    const float* lob_feat   = (const float*)d_in[0];
    const float* trade_feat = (const float*)d_in[1];
    const float* has_trade  = (const float*)d_in[2];
    const float* ei_w       = (const float*)d_in[3];
    const float* ei_b       = (const float*)d_in[4];
    const float* ei_g       = (const float*)d_in[5];
    const float* ei_beta    = (const float*)d_in[6];
    const float* decay      = (const float*)d_in[7];
    const float* in_proj_w  = (const float*)d_in[8];
    const float* in_proj_b  = (const float*)d_in[9];
    const float* out_proj_w = (const float*)d_in[10];
    const float* out_proj_b = (const float*)d_in[11];
    const float* cn_g       = (const float*)d_in[12];
    const float* cn_b       = (const float*)d_in[13];
    const float* lob_w      = (const float*)d_in[14];
    const float* lob_b      = (const float*)d_in[15];
    const float* lob_g      = (const float*)d_in[16];
    const float* lob_beta   = (const float*)d_in[17];
    const float* tr_w       = (const float*)d_in[18];
    const float* tr_b       = (const float*)d_in[19];
    const float* tr_g       = (const float*)d_in[20];
    const float* tr_beta    = (const float*)d_in[21];
    const float* of_w       = (const float*)d_in[22];
    const float* of_b       = (const float*)d_in[23];
    const float* of_g       = (const float*)d_in[24];
    const float* of_beta    = (const float*)d_in[25];

    char* W = (char*)d_ws;
    const size_t MB = 1u << 20;
    ushort_t* lobe_b   = (ushort_t*)W;               // 0-4 MB
    float*    carry    = (float*)(W + 8 * MB);
    float*    ends     = (float*)(W + 8 * MB + 256 * 1024);
    ushort_t* pool     = (ushort_t*)(W + 9 * MB);    // 9-17.75 MB
    ushort_t* imp_bf   = (ushort_t*)(W + 18 * MB);   // 18-22
    ushort_t* state_bf = (ushort_t*)(W + 22 * MB);
    ushort_t* tre_bf   = (ushort_t*)(W + 26 * MB);
    ushort_t* q_bf     = (ushort_t*)(W + 30 * MB);
    ushort_t* k_bf     = (ushort_t*)(W + 34 * MB);
    ushort_t* vt_g     = (ushort_t*)(W + 38 * MB);
    ushort_t* part     = (ushort_t*)(W + 42 * MB);   // 2 x 4 MB ctx partials
    float*    rs_part  = (float*)(W + 50 * MB);      // 512 KB
    float*    m_part   = (float*)(W + 50 * MB + 512 * 1024);

    ushort_t* lob_bf   = pool;
    ushort_t* trade_bf = pool + 2097152;
    ushort_t* eiw_bf   = pool + 4194304;
    ushort_t* ipw_bf   = pool + 4210688;
    ushort_t* opw_bf   = pool + 4259840;
    ushort_t* lobw_bf  = pool + 4276224;
    ushort_t* trw_bf   = pool + 4308992;
    ushort_t* ofw_bf   = pool + 4341760;

    ushort_t* ctxA = part;
    ushort_t* ctxB = part + 2097152;

    const dim3 blk(256);

    prep_kernel<<<dim3(2136), blk, 0, stream>>>(lob_feat, trade_feat, ei_w, in_proj_w,
                                                out_proj_w, lob_w, tr_w, of_w, pool);
    gemm_ei<<<dim3(512), blk, 0, stream>>>(trade_bf, eiw_bf, ei_b, ei_g, ei_beta,
                                           has_trade, imp_bf);
    scan_ends_kernel<<<dim3(32, 8), dim3(128), 0, stream>>>(imp_bf, decay, ends);
    scan_carry_kernel<<<dim3(8), dim3(128), 0, stream>>>(ends, decay, carry);
    scan_fin_kernel<<<dim3(32, 8), dim3(128), 0, stream>>>(imp_bf, decay, carry, state_bf);
    enh_qkv<<<dim3(512), blk, 0, stream>>>(lob_bf, trade_bf, state_bf, lobw_bf, trw_bf,
                                           ipw_bf, in_proj_b, lob_b, lob_g, lob_beta,
                                           tr_b, tr_g, tr_beta, lobe_b, tre_bf,
                                           q_bf, k_bf, vt_g);
    attn_kernel<<<dim3(32, 32), blk, 0, stream>>>(q_bf, k_bf, vt_g, part, rs_part, m_part);
    out_fuse<<<dim3(512), blk, 0, stream>>>(ctxA, ctxB, rs_part, m_part, tre_bf,
                                            opw_bf, out_proj_b, cn_g, cn_b,
                                            ofw_bf, of_b, of_g, of_beta, lobe_b, (float*)d_out);
}

// Round 14
// 137.814 us; speedup vs baseline: 1.0303x; 1.0303x over previous
//
#include <hip/hip_runtime.h>
#include <math.h>

// B=8, T=2048, D=128, NH=4, HD=32. BT=16384 rows.
// Round 14: r12 baseline (twice-verified 139.45/139.94us) with ONE change:
// s_setprio removed from attn (m190: setprio is negative on barrier-synced
// lockstep waves, which this attn is). Everything else identical to r12.

#define T_  2048

typedef short bf16x8 __attribute__((ext_vector_type(8)));
typedef float f32x4  __attribute__((ext_vector_type(4)));
typedef unsigned short ushort_t;

__device__ __forceinline__ float sigm(float x) { return 1.0f / (1.0f + __expf(-x)); }

__device__ __forceinline__ unsigned short f2bf(float x) {
    union { float f; unsigned u; } v; v.f = x;
    unsigned r = v.u + 0x7FFFu + ((v.u >> 16) & 1u);  // RNE
    return (unsigned short)(r >> 16);
}
__device__ __forceinline__ float bf2f(ushort_t u) {
    union { unsigned u; float f; } v; v.u = ((unsigned)u) << 16; return v.f;
}

__device__ __forceinline__ float gelu_f(float x) {
    const float e = exp2f(fmaf(0.044715f * x, x * x, x) * -2.3022083f);
    return x * __builtin_amdgcn_rcpf(1.0f + e);
}
__device__ __forceinline__ float tanh_f(float y) {
    const float e = exp2f(y * 2.8853900818f);
    return 1.0f - 2.0f * __builtin_amdgcn_rcpf(e + 1.0f);
}
#define MX3(a, b, c) fmaxf(fmaxf((a), (b)), (c))

// ---------------- prep: f32 -> bf16 for inputs + all weights -----------------
__global__ __launch_bounds__(256) void prep_kernel(
    const float* __restrict__ lob, const float* __restrict__ trade,
    const float* __restrict__ eiw, const float* __restrict__ ipw,
    const float* __restrict__ opw, const float* __restrict__ lobw,
    const float* __restrict__ trw, const float* __restrict__ ofw,
    ushort_t* __restrict__ pool)
{
    const size_t i8 = ((size_t)blockIdx.x * 256 + threadIdx.x) * 8;
    const float* src; size_t off;
    if      (i8 < 2097152) { src = lob;   off = 0; }
    else if (i8 < 4194304) { src = trade; off = 2097152; }
    else if (i8 < 4210688) { src = eiw;   off = 4194304; }
    else if (i8 < 4259840) { src = ipw;   off = 4210688; }
    else if (i8 < 4276224) { src = opw;   off = 4259840; }
    else if (i8 < 4308992) { src = lobw;  off = 4276224; }
    else if (i8 < 4341760) { src = trw;   off = 4308992; }
    else                   { src = ofw;   off = 4341760; }
    const float4 a = *(const float4*)(src + (i8 - off));
    const float4 b = *(const float4*)(src + (i8 - off) + 4);
    bf16x8 o;
    o[0] = (short)f2bf(a.x); o[1] = (short)f2bf(a.y);
    o[2] = (short)f2bf(a.z); o[3] = (short)f2bf(a.w);
    o[4] = (short)f2bf(b.x); o[5] = (short)f2bf(b.y);
    o[6] = (short)f2bf(b.z); o[7] = (short)f2bf(b.w);
    *(bf16x8*)(pool + i8) = o;
}

// ---------------- ei GEMM + LN + tanh*extra -> bf16 impact -------------------
__global__ __launch_bounds__(256) void gemm_ei(
    const ushort_t* __restrict__ Xb0, const ushort_t* __restrict__ Wb,
    const float* __restrict__ bias, const float* __restrict__ gamma,
    const float* __restrict__ beta, const float* __restrict__ extra,
    ushort_t* __restrict__ outb)
{
    __shared__ float red[32][2][2];
    const int tid = threadIdx.x, wid = tid >> 6, lane = tid & 63;
    const int c2 = lane & 15, g = lane >> 4;
    const int rowblk = wid >> 1, chf = wid & 1, cb0 = chf * 4;
    const int R0 = blockIdx.x * 32 + rowblk * 16;

    f32x4 acc[4] = {};
#pragma unroll
    for (int ch = 0; ch < 4; ch++) {
        const bf16x8 a = *(const bf16x8*)(Xb0 + (size_t)(R0 + c2) * 128 + ch * 32 + g * 8);
#pragma unroll
        for (int j = 0; j < 4; j++) {
            const bf16x8 b = *(const bf16x8*)(Wb + (size_t)((cb0 + j) * 16 + c2) * 128 + ch * 32 + g * 8);
            acc[j] = __builtin_amdgcn_mfma_f32_16x16x32_bf16(a, b, acc[j], 0, 0, 0);
        }
    }
    float gm[4], bt[4];
#pragma unroll
    for (int j = 0; j < 4; j++) {
        const int col = (cb0 + j) * 16 + c2;
        const float bb = bias[col];
        gm[j] = gamma[col]; bt[j] = beta[col];
#pragma unroll
        for (int r = 0; r < 4; r++) acc[j][r] += bb;
    }
#pragma unroll
    for (int r = 0; r < 4; r++) {
        float s = 0.f, ss = 0.f;
#pragma unroll
        for (int j = 0; j < 4; j++) { const float v = acc[j][r]; s += v; ss = fmaf(v, v, ss); }
#pragma unroll
        for (int o = 8; o; o >>= 1) { s += __shfl_xor(s, o); ss += __shfl_xor(ss, o); }
        if (c2 == 0) {
            red[rowblk * 16 + 4 * g + r][chf][0] = s;
            red[rowblk * 16 + 4 * g + r][chf][1] = ss;
        }
    }
    __syncthreads();
#pragma unroll
    for (int r = 0; r < 4; r++) {
        const int lr = rowblk * 16 + 4 * g + r;
        const float S  = red[lr][0][0] + red[lr][1][0];
        const float SS = red[lr][0][1] + red[lr][1][1];
        const float mean = S * (1.0f / 128.0f);
        float var = SS * (1.0f / 128.0f) - mean * mean;
        var = fmaxf(var, 0.0f);
        const float rstd = rsqrtf(var + 1e-5f);
        const int R = blockIdx.x * 32 + lr;
        const float ext = extra[R];
#pragma unroll
        for (int j = 0; j < 4; j++) {
            const float y = (acc[j][r] - mean) * rstd * gm[j] + bt[j];
            outb[(size_t)R * 128 + (cb0 + j) * 16 + c2] = f2bf(tanh_f(y) * ext);
        }
    }
}

// ---------------- fused enh (lobe+tre) + qkv ---------------------------------
__global__ __launch_bounds__(256) void enh_qkv(
    const ushort_t* __restrict__ lobb, const ushort_t* __restrict__ trab,
    const ushort_t* __restrict__ stab,
    const ushort_t* __restrict__ lobw, const ushort_t* __restrict__ trw,
    const ushort_t* __restrict__ ipw, const float* __restrict__ ipb,
    const float* __restrict__ lob_b, const float* __restrict__ lob_g,
    const float* __restrict__ lob_beta,
    const float* __restrict__ tr_b, const float* __restrict__ tr_g,
    const float* __restrict__ tr_beta,
    ushort_t* __restrict__ lobe_b, ushort_t* __restrict__ tre_bf,
    ushort_t* __restrict__ qo, ushort_t* __restrict__ ko, ushort_t* __restrict__ vo)
{
    __shared__ ushort_t lob_t[32][136];
    __shared__ ushort_t tre_t[32][136];
    __shared__ ushort_t vls[128][36];
    __shared__ float red[32][2][4];
    const int tid = threadIdx.x, wid = tid >> 6, lane = tid & 63;
    const int c2 = lane & 15, g = lane >> 4;
    const int rowblk = wid >> 1, chf = wid & 1, cb0 = chf * 4;
    const int RB = blockIdx.x * 32;
    const int R0 = RB + rowblk * 16;

    f32x4 aL[4] = {}, aT[4] = {};
#pragma unroll
    for (int ch = 0; ch < 8; ch++) {
        const int kk = (ch & 3) * 32;
        bf16x8 xl, xt;
        if (ch < 4) {
            xl = *(const bf16x8*)(lobb + (size_t)(R0 + c2) * 128 + kk + g * 8);
            xt = *(const bf16x8*)(trab + (size_t)(R0 + c2) * 128 + kk + g * 8);
        } else {
            xl = *(const bf16x8*)(stab + (size_t)(R0 + c2) * 128 + kk + g * 8);
            xt = xl;
        }
#pragma unroll
        for (int j = 0; j < 4; j++) {
            const size_t wo = (size_t)((cb0 + j) * 16 + c2) * 256 + ch * 32 + g * 8;
            aL[j] = __builtin_amdgcn_mfma_f32_16x16x32_bf16(xl, *(const bf16x8*)(lobw + wo), aL[j], 0, 0, 0);
            aT[j] = __builtin_amdgcn_mfma_f32_16x16x32_bf16(xt, *(const bf16x8*)(trw + wo), aT[j], 0, 0, 0);
        }
    }
#pragma unroll
    for (int j = 0; j < 4; j++) {
        const int col = (cb0 + j) * 16 + c2;
        const float bL = lob_b[col], bT = tr_b[col];
#pragma unroll
        for (int r = 0; r < 4; r++) { aL[j][r] += bL; aT[j][r] += bT; }
    }
#pragma unroll
    for (int r = 0; r < 4; r++) {
        float sL = 0.f, ssL = 0.f, sT = 0.f, ssT = 0.f;
#pragma unroll
        for (int j = 0; j < 4; j++) {
            const float vL = aL[j][r], vT = aT[j][r];
            sL += vL; ssL = fmaf(vL, vL, ssL);
            sT += vT; ssT = fmaf(vT, vT, ssT);
        }
#pragma unroll
        for (int o = 8; o; o >>= 1) {
            sL += __shfl_xor(sL, o); ssL += __shfl_xor(ssL, o);
            sT += __shfl_xor(sT, o); ssT += __shfl_xor(ssT, o);
        }
        if (c2 == 0) {
            float* rd = red[rowblk * 16 + 4 * g + r][chf];
            rd[0] = sL; rd[1] = ssL; rd[2] = sT; rd[3] = ssT;
        }
    }
    __syncthreads();
#pragma unroll
    for (int r = 0; r < 4; r++) {
        const int lr = rowblk * 16 + 4 * g + r;
        const int R = RB + lr;
        const float SL  = red[lr][0][0] + red[lr][1][0];
        const float SSL = red[lr][0][1] + red[lr][1][1];
        const float ST  = red[lr][0][2] + red[lr][1][2];
        const float SST = red[lr][0][3] + red[lr][1][3];
        const float mL = SL * (1.0f / 128.0f), mT = ST * (1.0f / 128.0f);
        const float rL = rsqrtf(fmaxf(SSL * (1.0f / 128.0f) - mL * mL, 0.0f) + 1e-5f);
        const float rT = rsqrtf(fmaxf(SST * (1.0f / 128.0f) - mT * mT, 0.0f) + 1e-5f);
#pragma unroll
        for (int j = 0; j < 4; j++) {
            const int col = (cb0 + j) * 16 + c2;
            const float yL = gelu_f((aL[j][r] - mL) * rL * lob_g[col] + lob_beta[col]);
            const float yT = gelu_f((aT[j][r] - mT) * rT * tr_g[col] + tr_beta[col]);
            const ushort_t lb = f2bf(yL);
            lobe_b[(size_t)R * 128 + col] = lb;
            lob_t[lr][col] = lb;
            const ushort_t tb = f2bf(yT);
            tre_bf[(size_t)R * 128 + col] = tb;
            tre_t[lr][col] = tb;
        }
    }
    __syncthreads();

    const float qscale = 0.17677669529663687f * 1.4426950408889634f;
#pragma unroll
    for (int which = 0; which < 3; which++) {
        const ushort_t (*src)[136] = (which == 0) ? lob_t : tre_t;
        const ushort_t* Wp = ipw + (size_t)which * 16384;
        f32x4 pa[4] = {};
#pragma unroll
        for (int ch = 0; ch < 4; ch++) {
            const bf16x8 a = *(const bf16x8*)&src[rowblk * 16 + c2][ch * 32 + g * 8];
#pragma unroll
            for (int j = 0; j < 4; j++) {
                const bf16x8 b = *(const bf16x8*)(Wp + (size_t)((cb0 + j) * 16 + c2) * 128 + ch * 32 + g * 8);
                pa[j] = __builtin_amdgcn_mfma_f32_16x16x32_bf16(a, b, pa[j], 0, 0, 0);
            }
        }
        if (which < 2) {
            ushort_t* dst = (which == 0) ? qo : ko;
            const float sc = (which == 0) ? qscale : 1.0f;
#pragma unroll
            for (int j = 0; j < 4; j++) {
                const int col = (cb0 + j) * 16 + c2;
                const float bb = ipb[which * 128 + col];
                const int h = col >> 5, hd = col & 31;
#pragma unroll
                for (int r = 0; r < 4; r++) {
                    const int R = R0 + 4 * g + r;
                    const int b = R >> 11, t = R & 2047;
                    dst[(((size_t)b * 4 + h) * 2048 + t) * 32 + hd] = f2bf((pa[j][r] + bb) * sc);
                }
            }
        } else {
#pragma unroll
            for (int j = 0; j < 4; j++) {
                const int col = (cb0 + j) * 16 + c2;
                const float bb = ipb[256 + col];
#pragma unroll
                for (int r = 0; r < 4; r++)
                    vls[col][rowblk * 16 + 4 * g + r] = f2bf(pa[j][r] + bb);
            }
        }
    }
    __syncthreads();
    // V^T global write with kappa permutation (PV B-frag = lane's own words)
    {
        const int col = tid >> 1, hf = tid & 1;
        const int h = col >> 5, hd = col & 31;
        const int b = RB >> 11;
        unsigned w[8];
#pragma unroll
        for (int e = 0; e < 8; e++) {
            const int p0 = hf * 16 + 2 * e;
            const int g2 = p0 >> 3, j2 = p0 & 7;
            const int lk = 4 * g2 + j2 + (j2 >= 4 ? 12 : 0);
            w[e] = (unsigned)vls[col][lk] | ((unsigned)vls[col][lk + 1] << 16);
        }
        ushort_t* dst = vo + (((size_t)b * 4 + h) * 32 + hd) * 2048 + (RB & 2047) + hf * 16;
        *(uint4*)dst       = *(const uint4*)&w[0];
        *(uint4*)(dst + 8) = *(const uint4*)&w[4];
    }
}

// ---------------- flash attention: split-K x2, ctx-layout partials -----------
__global__ __launch_bounds__(256) void attn_kernel(
    const ushort_t* __restrict__ q, const ushort_t* __restrict__ k,
    const ushort_t* __restrict__ vtg,
    ushort_t* __restrict__ part, float* __restrict__ rs_part,
    float* __restrict__ m_part)
{
    __shared__ ushort_t ks[2][64][40];   // K tile   [buf][key][hd]
    __shared__ ushort_t vt[2][32][72];   // V^T tile [buf][d][kappa-pos]
    const int tid = threadIdx.x, wid = tid >> 6, lane = tid & 63;
    const int c = lane & 15, g = lane >> 4;
    const int half = blockIdx.x & 1, qt = blockIdx.x >> 1;
    const int bh = blockIdx.y, b = bh >> 2, h = bh & 3;
    const ushort_t* kb_ = k   + (size_t)bh * 65536 + (size_t)half * 1024 * 32;
    const ushort_t* vb_ = vtg + (size_t)bh * 65536 + (size_t)half * 1024;
    const int q0 = qt * 128 + wid * 32;

    const ushort_t* qbase = q + ((size_t)bh * 2048 + q0) * 32;
    const bf16x8 qf0 = *(const bf16x8*)(qbase + (size_t)c * 32 + g * 8);
    const bf16x8 qf1 = *(const bf16x8*)(qbase + (size_t)(16 + c) * 32 + g * 8);

    bf16x8 ones;
#pragma unroll
    for (int i = 0; i < 8; i++) ones[i] = (short)0x3F80;

    float m0 = 0.0f, m1 = 0.0f;
    f32x4 acc[2][2] = {};
    f32x4 racc[2] = {};

    const int srow = tid >> 2, ssg = tid & 3;  // K staging
    const int vd = tid >> 3, vkg = tid & 7;    // V^T staging

    {
        const bf16x8 kk8 = *(const bf16x8*)(kb_ + (size_t)srow * 32 + ssg * 8);
        const bf16x8 vv8 = *(const bf16x8*)(vb_ + (size_t)vd * 2048 + vkg * 8);
        *(bf16x8*)&ks[0][srow][ssg * 8] = kk8;
        *(bf16x8*)&vt[0][vd][vkg * 8] = vv8;
    }
    __syncthreads();

    for (int kt = 0; kt < 16; kt++) {
        const int cur = kt & 1;
        bf16x8 kk8, vv8;
        if (kt + 1 < 16) {
            kk8 = *(const bf16x8*)(kb_ + ((size_t)(kt + 1) * 64 + srow) * 32 + ssg * 8);
            vv8 = *(const bf16x8*)(vb_ + (size_t)vd * 2048 + (kt + 1) * 64 + vkg * 8);
        }

        // ---- QK^T swapped: C[key][q]; kf shared by both Q frags ----
        f32x4 s0[4], s1[4];
#pragma unroll
        for (int kb2 = 0; kb2 < 4; kb2++) {
            const bf16x8 kf = *(const bf16x8*)&ks[cur][kb2 * 16 + c][g * 8];
            f32x4 z = {};
            s0[kb2] = __builtin_amdgcn_mfma_f32_16x16x32_bf16(kf, qf0, z, 0, 0, 0);
            s1[kb2] = __builtin_amdgcn_mfma_f32_16x16x32_bf16(kf, qf1, z, 0, 0, 0);
        }

        // ---- guard: max3 triples ----
        float lm = MX3(s0[0][0], s0[0][1], s0[0][2]);
        lm = MX3(lm, s0[0][3], s0[1][0]);
        lm = MX3(lm, s0[1][1], s0[1][2]);
        lm = MX3(lm, s0[1][3], s0[2][0]);
        lm = MX3(lm, s0[2][1], s0[2][2]);
        lm = MX3(lm, s0[2][3], s0[3][0]);
        lm = MX3(lm, s0[3][1], s0[3][2]);
        lm = MX3(lm, s0[3][3], s1[0][0]);
        lm = MX3(lm, s1[0][1], s1[0][2]);
        lm = MX3(lm, s1[0][3], s1[1][0]);
        lm = MX3(lm, s1[1][1], s1[1][2]);
        lm = MX3(lm, s1[1][3], s1[2][0]);
        lm = MX3(lm, s1[2][1], s1[2][2]);
        lm = MX3(lm, s1[2][3], s1[3][0]);
        lm = MX3(lm, s1[3][1], s1[3][2]);
        lm = fmaxf(lm, s1[3][3]);
        if (__any(lm > 80.0f || m0 != 0.0f || m1 != 0.0f)) {
            // true online-softmax (rare; correct under any data)
            float l0 = -1e30f, l1 = -1e30f;
#pragma unroll
            for (int kb2 = 0; kb2 < 4; kb2++) {
#pragma unroll
                for (int r = 0; r < 4; r++) { l0 = fmaxf(l0, s0[kb2][r]); l1 = fmaxf(l1, s1[kb2][r]); }
            }
            l0 = fmaxf(l0, __shfl_xor(l0, 16)); l0 = fmaxf(l0, __shfl_xor(l0, 32));
            l1 = fmaxf(l1, __shfl_xor(l1, 16)); l1 = fmaxf(l1, __shfl_xor(l1, 32));
            const float n0 = fmaxf(m0, l0), n1 = fmaxf(m1, l1);
            const float a0 = exp2f(m0 - n0), a1 = exp2f(m1 - n1);
#pragma unroll
            for (int nb = 0; nb < 2; nb++)
#pragma unroll
                for (int r = 0; r < 4; r++) { acc[0][nb][r] *= a0; acc[1][nb][r] *= a1; }
#pragma unroll
            for (int r = 0; r < 4; r++) { racc[0][r] *= a0; racc[1][r] *= a1; }
            m0 = n0; m1 = n1;
#pragma unroll
            for (int kb2 = 0; kb2 < 4; kb2++)
#pragma unroll
                for (int r = 0; r < 4; r++) {
                    s0[kb2][r] = exp2f(s0[kb2][r] - m0);
                    s1[kb2][r] = exp2f(s1[kb2][r] - m1);
                }
        } else {
            // fast path: m == 0, no subtraction
#pragma unroll
            for (int kb2 = 0; kb2 < 4; kb2++)
#pragma unroll
                for (int r = 0; r < 4; r++) {
                    s0[kb2][r] = exp2f(s0[kb2][r]);
                    s1[kb2][r] = exp2f(s1[kb2][r]);
                }
        }

        // ---- pack P to bf16 (lane-local; kappa layout matches V^T) ----
        union { unsigned u[4]; bf16x8 v; } p0a, p0b, p1a, p1b;
        asm("v_cvt_pk_bf16_f32 %0, %1, %2" : "=v"(p0a.u[0]) : "v"(s0[0][0]), "v"(s0[0][1]));
        asm("v_cvt_pk_bf16_f32 %0, %1, %2" : "=v"(p0a.u[1]) : "v"(s0[0][2]), "v"(s0[0][3]));
        asm("v_cvt_pk_bf16_f32 %0, %1, %2" : "=v"(p0a.u[2]) : "v"(s0[1][0]), "v"(s0[1][1]));
        asm("v_cvt_pk_bf16_f32 %0, %1, %2" : "=v"(p0a.u[3]) : "v"(s0[1][2]), "v"(s0[1][3]));
        asm("v_cvt_pk_bf16_f32 %0, %1, %2" : "=v"(p0b.u[0]) : "v"(s0[2][0]), "v"(s0[2][1]));
        asm("v_cvt_pk_bf16_f32 %0, %1, %2" : "=v"(p0b.u[1]) : "v"(s0[2][2]), "v"(s0[2][3]));
        asm("v_cvt_pk_bf16_f32 %0, %1, %2" : "=v"(p0b.u[2]) : "v"(s0[3][0]), "v"(s0[3][1]));
        asm("v_cvt_pk_bf16_f32 %0, %1, %2" : "=v"(p0b.u[3]) : "v"(s0[3][2]), "v"(s0[3][3]));
        asm("v_cvt_pk_bf16_f32 %0, %1, %2" : "=v"(p1a.u[0]) : "v"(s1[0][0]), "v"(s1[0][1]));
        asm("v_cvt_pk_bf16_f32 %0, %1, %2" : "=v"(p1a.u[1]) : "v"(s1[0][2]), "v"(s1[0][3]));
        asm("v_cvt_pk_bf16_f32 %0, %1, %2" : "=v"(p1a.u[2]) : "v"(s1[1][0]), "v"(s1[1][1]));
        asm("v_cvt_pk_bf16_f32 %0, %1, %2" : "=v"(p1a.u[3]) : "v"(s1[1][2]), "v"(s1[1][3]));
        asm("v_cvt_pk_bf16_f32 %0, %1, %2" : "=v"(p1b.u[0]) : "v"(s1[2][0]), "v"(s1[2][1]));
        asm("v_cvt_pk_bf16_f32 %0, %1, %2" : "=v"(p1b.u[1]) : "v"(s1[2][2]), "v"(s1[2][3]));
        asm("v_cvt_pk_bf16_f32 %0, %1, %2" : "=v"(p1b.u[2]) : "v"(s1[3][0]), "v"(s1[3][1]));
        asm("v_cvt_pk_bf16_f32 %0, %1, %2" : "=v"(p1b.u[3]) : "v"(s1[3][2]), "v"(s1[3][3]));

        // ---- PV + denominator (all on matrix pipe) ----
#pragma unroll
        for (int nb = 0; nb < 2; nb++) {
            const bf16x8 v0 = *(const bf16x8*)&vt[cur][nb * 16 + c][g * 8];
            const bf16x8 v1 = *(const bf16x8*)&vt[cur][nb * 16 + c][32 + g * 8];
            acc[0][nb] = __builtin_amdgcn_mfma_f32_16x16x32_bf16(v0, p0a.v, acc[0][nb], 0, 0, 0);
            acc[0][nb] = __builtin_amdgcn_mfma_f32_16x16x32_bf16(v1, p0b.v, acc[0][nb], 0, 0, 0);
            acc[1][nb] = __builtin_amdgcn_mfma_f32_16x16x32_bf16(v0, p1a.v, acc[1][nb], 0, 0, 0);
            acc[1][nb] = __builtin_amdgcn_mfma_f32_16x16x32_bf16(v1, p1b.v, acc[1][nb], 0, 0, 0);
        }
        racc[0] = __builtin_amdgcn_mfma_f32_16x16x32_bf16(ones, p0a.v, racc[0], 0, 0, 0);
        racc[0] = __builtin_amdgcn_mfma_f32_16x16x32_bf16(ones, p0b.v, racc[0], 0, 0, 0);
        racc[1] = __builtin_amdgcn_mfma_f32_16x16x32_bf16(ones, p1a.v, racc[1], 0, 0, 0);
        racc[1] = __builtin_amdgcn_mfma_f32_16x16x32_bf16(ones, p1b.v, racc[1], 0, 0, 0);

        if (kt + 1 < 16) {
            *(bf16x8*)&ks[cur ^ 1][srow][ssg * 8] = kk8;
            *(bf16x8*)&vt[cur ^ 1][vd][vkg * 8] = vv8;
        }
        __syncthreads();
    }

    // ---- partial store in ctx layout: part[half][b][t][h*32+d] (uint2) ------
    ushort_t* pb = part + (size_t)half * 2097152;
#pragma unroll
    for (int qf = 0; qf < 2; qf++) {
        const int qrow = q0 + qf * 16 + c;
        ushort_t* dst = pb + ((size_t)(b * 2048 + qrow)) * 128 + h * 32;
#pragma unroll
        for (int nb = 0; nb < 2; nb++) {
            unsigned w0, w1;
            asm("v_cvt_pk_bf16_f32 %0, %1, %2" : "=v"(w0) : "v"(acc[qf][nb][0]), "v"(acc[qf][nb][1]));
            asm("v_cvt_pk_bf16_f32 %0, %1, %2" : "=v"(w1) : "v"(acc[qf][nb][2]), "v"(acc[qf][nb][3]));
            uint2 wv; wv.x = w0; wv.y = w1;
            *(uint2*)(dst + nb * 16 + 4 * g) = wv;
        }
    }
    if (g == 0) {
        float* rsp = rs_part + (size_t)(half * 32 + bh) * 2048;
        float* mp  = m_part  + (size_t)(half * 32 + bh) * 2048;
        rsp[q0 + c]      = racc[0][0];
        rsp[q0 + 16 + c] = racc[1][0];
        mp[q0 + c]       = m0;
        mp[q0 + 16 + c]  = m1;
    }
}

// ------- fused split-K combine + out-proj + residual-LN + final GEMM ---------
__global__ __launch_bounds__(256) void out_fuse(
    const ushort_t* __restrict__ ctxA, const ushort_t* __restrict__ ctxB,
    const float* __restrict__ rs_part, const float* __restrict__ m_part,
    const ushort_t* __restrict__ treb,
    const ushort_t* __restrict__ opw, const float* __restrict__ opb,
    const float* __restrict__ cn_g, const float* __restrict__ cn_b,
    const ushort_t* __restrict__ ofw, const float* __restrict__ of_b,
    const float* __restrict__ of_g, const float* __restrict__ of_beta,
    const ushort_t* __restrict__ lobe_b, float* __restrict__ out)
{
    __shared__ ushort_t fus_t[32][136];
    __shared__ float red[32][2][2];
    const int tid = threadIdx.x, wid = tid >> 6, lane = tid & 63;
    const int c2 = lane & 15, g = lane >> 4;
    const int rowblk = wid >> 1, chf = wid & 1, cb0 = chf * 4;
    const int RB = blockIdx.x * 32;
    const int R0 = RB + rowblk * 16;

    // ---- per-lane-row, per-head combine factors ----
    const int rowA = R0 + c2;
    const int bb2 = rowA >> 11, tt = rowA & 2047;
    float fA[4], fB[4];
#pragma unroll
    for (int h = 0; h < 4; h++) {
        const int bh = bb2 * 4 + h;
        const float mA = m_part[(size_t)bh * 2048 + tt];
        const float mB = m_part[(size_t)(32 + bh) * 2048 + tt];
        const float rA = rs_part[(size_t)bh * 2048 + tt];
        const float rB = rs_part[(size_t)(32 + bh) * 2048 + tt];
        const float M = fmaxf(mA, mB);
        const float wA = exp2f(mA - M), wB = exp2f(mB - M);
        const float inv = __builtin_amdgcn_rcpf(fmaf(rA, wA, rB * wB));
        fA[h] = wA * inv; fB[h] = wB * inv;
    }

    // ---- phase A: fused = LN(lobe + combined_ctx @ opw + opb) ----
    f32x4 acc[4] = {};
#pragma unroll
    for (int ch = 0; ch < 4; ch++) {
        const bf16x8 aA = *(const bf16x8*)(ctxA + (size_t)rowA * 128 + ch * 32 + g * 8);
        const bf16x8 aB = *(const bf16x8*)(ctxB + (size_t)rowA * 128 + ch * 32 + g * 8);
        union { unsigned u[4]; bf16x8 v; } am;
#pragma unroll
        for (int i = 0; i < 4; i++) {
            const float e0 = bf2f((ushort_t)aA[2 * i]) * fA[ch] + bf2f((ushort_t)aB[2 * i]) * fB[ch];
            const float e1 = bf2f((ushort_t)aA[2 * i + 1]) * fA[ch] + bf2f((ushort_t)aB[2 * i + 1]) * fB[ch];
            asm("v_cvt_pk_bf16_f32 %0, %1, %2" : "=v"(am.u[i]) : "v"(e0), "v"(e1));
        }
#pragma unroll
        for (int j = 0; j < 4; j++) {
            const bf16x8 b = *(const bf16x8*)(opw + (size_t)((cb0 + j) * 16 + c2) * 128 + ch * 32 + g * 8);
            acc[j] = __builtin_amdgcn_mfma_f32_16x16x32_bf16(am.v, b, acc[j], 0, 0, 0);
        }
    }
#pragma unroll
    for (int j = 0; j < 4; j++) {
        const int col = (cb0 + j) * 16 + c2;
        const float bb = opb[col];
#pragma unroll
        for (int r = 0; r < 4; r++)
            acc[j][r] += bb + bf2f(lobe_b[(size_t)(R0 + 4 * g + r) * 128 + col]);
    }
#pragma unroll
    for (int r = 0; r < 4; r++) {
        float s = 0.f, ss = 0.f;
#pragma unroll
        for (int j = 0; j < 4; j++) { const float v = acc[j][r]; s += v; ss = fmaf(v, v, ss); }
#pragma unroll
        for (int o = 8; o; o >>= 1) { s += __shfl_xor(s, o); ss += __shfl_xor(ss, o); }
        if (c2 == 0) {
            red[rowblk * 16 + 4 * g + r][chf][0] = s;
            red[rowblk * 16 + 4 * g + r][chf][1] = ss;
        }
    }
    __syncthreads();
#pragma unroll
    for (int r = 0; r < 4; r++) {
        const int lr = rowblk * 16 + 4 * g + r;
        const float S  = red[lr][0][0] + red[lr][1][0];
        const float SS = red[lr][0][1] + red[lr][1][1];
        const float mean = S * (1.0f / 128.0f);
        const float rstd = rsqrtf(fmaxf(SS * (1.0f / 128.0f) - mean * mean, 0.0f) + 1e-5f);
#pragma unroll
        for (int j = 0; j < 4; j++) {
            const int col = (cb0 + j) * 16 + c2;
            fus_t[lr][col] = f2bf((acc[j][r] - mean) * rstd * cn_g[col] + cn_b[col]);
        }
    }
    __syncthreads();

    // ---- phase B: out = gelu(LN([fused, tre]@ofw + ofb)) ----
    f32x4 a2[4] = {};
#pragma unroll
    for (int ch = 0; ch < 8; ch++) {
        bf16x8 a;
        if (ch < 4) a = *(const bf16x8*)&fus_t[rowblk * 16 + c2][ch * 32 + g * 8];
        else        a = *(const bf16x8*)(treb + (size_t)(R0 + c2) * 128 + (ch - 4) * 32 + g * 8);
#pragma unroll
        for (int j = 0; j < 4; j++) {
            const bf16x8 b = *(const bf16x8*)(ofw + (size_t)((cb0 + j) * 16 + c2) * 256 + ch * 32 + g * 8);
            a2[j] = __builtin_amdgcn_mfma_f32_16x16x32_bf16(a, b, a2[j], 0, 0, 0);
        }
    }
#pragma unroll
    for (int j = 0; j < 4; j++) {
        const float bb = of_b[(cb0 + j) * 16 + c2];
#pragma unroll
        for (int r = 0; r < 4; r++) a2[j][r] += bb;
    }
#pragma unroll
    for (int r = 0; r < 4; r++) {
        float s = 0.f, ss = 0.f;
#pragma unroll
        for (int j = 0; j < 4; j++) { const float v = a2[j][r]; s += v; ss = fmaf(v, v, ss); }
#pragma unroll
        for (int o = 8; o; o >>= 1) { s += __shfl_xor(s, o); ss += __shfl_xor(ss, o); }
        if (c2 == 0) {
            red[rowblk * 16 + 4 * g + r][chf][0] = s;
            red[rowblk * 16 + 4 * g + r][chf][1] = ss;
        }
    }
    __syncthreads();
#pragma unroll
    for (int r = 0; r < 4; r++) {
        const int lr = rowblk * 16 + 4 * g + r;
        const float S  = red[lr][0][0] + red[lr][1][0];
        const float SS = red[lr][0][1] + red[lr][1][1];
        const float mean = S * (1.0f / 128.0f);
        const float rstd = rsqrtf(fmaxf(SS * (1.0f / 128.0f) - mean * mean, 0.0f) + 1e-5f);
        const int R = RB + lr;
#pragma unroll
        for (int j = 0; j < 4; j++) {
            const int col = (cb0 + j) * 16 + c2;
            const float y = (a2[j][r] - mean) * rstd * of_g[col] + of_beta[col];
            out[(size_t)R * 128 + col] = gelu_f(y);
        }
    }
}

// ---------------- decay scan: ends -> carry -> re-scan -----------------------
__global__ void scan_ends_kernel(const ushort_t* __restrict__ imp,
                                 const float* __restrict__ decay,
                                 float* __restrict__ ends)
{
    const int c = threadIdx.x;
    const int ch = blockIdx.x, b = blockIdx.y;
    const float d = sigm(decay[c]);
    const size_t base = ((size_t)b * T_ + ch * 64) * 128 + c;
    float s = 0.0f;
#pragma unroll 4
    for (int tl = 0; tl < 64; tl++)
        s = fmaf(d, s, bf2f(imp[base + (size_t)tl * 128]));
    ends[((size_t)b * 32 + ch) * 128 + c] = s;
}

__global__ void scan_carry_kernel(const float* __restrict__ ends,
                                  const float* __restrict__ decay,
                                  float* __restrict__ carry)
{
    const int c = threadIdx.x;
    const int b = blockIdx.x;
    const float d = sigm(decay[c]);
    float dl = d;
#pragma unroll
    for (int i = 0; i < 6; i++) dl *= dl;  // d^64
    float e = 0.0f;
#pragma unroll
    for (int ch = 0; ch < 32; ch++) {
        carry[((size_t)b * 32 + ch) * 128 + c] = e;
        e = fmaf(dl, e, ends[((size_t)b * 32 + ch) * 128 + c]);
    }
}

__global__ void scan_fin_kernel(const ushort_t* __restrict__ imp,
                                const float* __restrict__ decay,
                                const float* __restrict__ carry,
                                ushort_t* __restrict__ stbf)
{
    const int c = threadIdx.x;
    const int ch = blockIdx.x, b = blockIdx.y;
    const float d = sigm(decay[c]);
    float s = carry[((size_t)b * 32 + ch) * 128 + c];
    const size_t base = ((size_t)b * T_ + ch * 64) * 128 + c;
#pragma unroll 4
    for (int tl = 0; tl < 64; tl++) {
        s = fmaf(d, s, bf2f(imp[base + (size_t)tl * 128]));
        stbf[base + (size_t)tl * 128] = f2bf(s);
    }
}

extern "C" void kernel_launch(void* const* d_in, const int* in_sizes, int n_in,
                              void* d_out, int out_size, void* d_ws, size_t ws_size,
                              hipStream_t stream)
{
    const float* lob_feat   = (const float*)d_in[0];
    const float* trade_feat = (const float*)d_in[1];
    const float* has_trade  = (const float*)d_in[2];
    const float* ei_w       = (const float*)d_in[3];
    const float* ei_b       = (const float*)d_in[4];
    const float* ei_g       = (const float*)d_in[5];
    const float* ei_beta    = (const float*)d_in[6];
    const float* decay      = (const float*)d_in[7];
    const float* in_proj_w  = (const float*)d_in[8];
    const float* in_proj_b  = (const float*)d_in[9];
    const float* out_proj_w = (const float*)d_in[10];
    const float* out_proj_b = (const float*)d_in[11];
    const float* cn_g       = (const float*)d_in[12];
    const float* cn_b       = (const float*)d_in[13];
    const float* lob_w      = (const float*)d_in[14];
    const float* lob_b      = (const float*)d_in[15];
    const float* lob_g      = (const float*)d_in[16];
    const float* lob_beta   = (const float*)d_in[17];
    const float* tr_w       = (const float*)d_in[18];
    const float* tr_b       = (const float*)d_in[19];
    const float* tr_g       = (const float*)d_in[20];
    const float* tr_beta    = (const float*)d_in[21];
    const float* of_w       = (const float*)d_in[22];
    const float* of_b       = (const float*)d_in[23];
    const float* of_g       = (const float*)d_in[24];
    const float* of_beta    = (const float*)d_in[25];

    char* W = (char*)d_ws;
    const size_t MB = 1u << 20;
    ushort_t* lobe_b   = (ushort_t*)W;               // 0-4 MB
    float*    carry    = (float*)(W + 8 * MB);
    float*    ends     = (float*)(W + 8 * MB + 256 * 1024);
    ushort_t* pool     = (ushort_t*)(W + 9 * MB);    // 9-17.75 MB
    ushort_t* imp_bf   = (ushort_t*)(W + 18 * MB);   // 18-22
    ushort_t* state_bf = (ushort_t*)(W + 22 * MB);
    ushort_t* tre_bf   = (ushort_t*)(W + 26 * MB);
    ushort_t* q_bf     = (ushort_t*)(W + 30 * MB);
    ushort_t* k_bf     = (ushort_t*)(W + 34 * MB);
    ushort_t* vt_g     = (ushort_t*)(W + 38 * MB);
    ushort_t* part     = (ushort_t*)(W + 42 * MB);   // 2 x 4 MB ctx partials
    float*    rs_part  = (float*)(W + 50 * MB);      // 512 KB
    float*    m_part   = (float*)(W + 50 * MB + 512 * 1024);

    ushort_t* lob_bf   = pool;
    ushort_t* trade_bf = pool + 2097152;
    ushort_t* eiw_bf   = pool + 4194304;
    ushort_t* ipw_bf   = pool + 4210688;
    ushort_t* opw_bf   = pool + 4259840;
    ushort_t* lobw_bf  = pool + 4276224;
    ushort_t* trw_bf   = pool + 4308992;
    ushort_t* ofw_bf   = pool + 4341760;

    ushort_t* ctxA = part;
    ushort_t* ctxB = part + 2097152;

    const dim3 blk(256);

    prep_kernel<<<dim3(2136), blk, 0, stream>>>(lob_feat, trade_feat, ei_w, in_proj_w,
                                                out_proj_w, lob_w, tr_w, of_w, pool);
    gemm_ei<<<dim3(512), blk, 0, stream>>>(trade_bf, eiw_bf, ei_b, ei_g, ei_beta,
                                           has_trade, imp_bf);
    scan_ends_kernel<<<dim3(32, 8), dim3(128), 0, stream>>>(imp_bf, decay, ends);
    scan_carry_kernel<<<dim3(8), dim3(128), 0, stream>>>(ends, decay, carry);
    scan_fin_kernel<<<dim3(32, 8), dim3(128), 0, stream>>>(imp_bf, decay, carry, state_bf);
    enh_qkv<<<dim3(512), blk, 0, stream>>>(lob_bf, trade_bf, state_bf, lobw_bf, trw_bf,
                                           ipw_bf, in_proj_b, lob_b, lob_g, lob_beta,
                                           tr_b, tr_g, tr_beta, lobe_b, tre_bf,
                                           q_bf, k_bf, vt_g);
    attn_kernel<<<dim3(32, 32), blk, 0, stream>>>(q_bf, k_bf, vt_g, part, rs_part, m_part);
    out_fuse<<<dim3(512), blk, 0, stream>>>(ctxA, ctxB, rs_part, m_part, tre_bf,
                                            opw_bf, out_proj_b, cn_g, cn_b,
                                            ofw_bf, of_b, of_g, of_beta, lobe_b, (float*)d_out);
}

// Round 15
// 132.472 us; speedup vs baseline: 1.0718x; 1.0403x over previous
//
#include <hip/hip_runtime.h>
#include <math.h>

// B=8, T=2048, D=128, NH=4, HD=32. BT=16384 rows.
// Round 15: r14 (best verified, 137.81us) with ONE change in attn softmax:
// optimistic exp2+pack issued BEFORE the overflow-guard branch resolves
// (s preserved; rare slow path recomputes packs exactly). Removes the
// max-tree+vote+branch serial prefix from the exp2 critical path.

#define T_  2048

typedef short bf16x8 __attribute__((ext_vector_type(8)));
typedef float f32x4  __attribute__((ext_vector_type(4)));
typedef unsigned short ushort_t;

__device__ __forceinline__ float sigm(float x) { return 1.0f / (1.0f + __expf(-x)); }

__device__ __forceinline__ unsigned short f2bf(float x) {
    union { float f; unsigned u; } v; v.f = x;
    unsigned r = v.u + 0x7FFFu + ((v.u >> 16) & 1u);  // RNE
    return (unsigned short)(r >> 16);
}
__device__ __forceinline__ float bf2f(ushort_t u) {
    union { unsigned u; float f; } v; v.u = ((unsigned)u) << 16; return v.f;
}
__device__ __forceinline__ unsigned cvtpk(float a, float b) {
    unsigned r;
    asm("v_cvt_pk_bf16_f32 %0, %1, %2" : "=v"(r) : "v"(a), "v"(b));
    return r;
}

__device__ __forceinline__ float gelu_f(float x) {
    const float e = exp2f(fmaf(0.044715f * x, x * x, x) * -2.3022083f);
    return x * __builtin_amdgcn_rcpf(1.0f + e);
}
__device__ __forceinline__ float tanh_f(float y) {
    const float e = exp2f(y * 2.8853900818f);
    return 1.0f - 2.0f * __builtin_amdgcn_rcpf(e + 1.0f);
}
#define MX3(a, b, c) fmaxf(fmaxf((a), (b)), (c))

// ---------------- prep: f32 -> bf16 for inputs + all weights -----------------
__global__ __launch_bounds__(256) void prep_kernel(
    const float* __restrict__ lob, const float* __restrict__ trade,
    const float* __restrict__ eiw, const float* __restrict__ ipw,
    const float* __restrict__ opw, const float* __restrict__ lobw,
    const float* __restrict__ trw, const float* __restrict__ ofw,
    ushort_t* __restrict__ pool)
{
    const size_t i8 = ((size_t)blockIdx.x * 256 + threadIdx.x) * 8;
    const float* src; size_t off;
    if      (i8 < 2097152) { src = lob;   off = 0; }
    else if (i8 < 4194304) { src = trade; off = 2097152; }
    else if (i8 < 4210688) { src = eiw;   off = 4194304; }
    else if (i8 < 4259840) { src = ipw;   off = 4210688; }
    else if (i8 < 4276224) { src = opw;   off = 4259840; }
    else if (i8 < 4308992) { src = lobw;  off = 4276224; }
    else if (i8 < 4341760) { src = trw;   off = 4308992; }
    else                   { src = ofw;   off = 4341760; }
    const float4 a = *(const float4*)(src + (i8 - off));
    const float4 b = *(const float4*)(src + (i8 - off) + 4);
    bf16x8 o;
    o[0] = (short)f2bf(a.x); o[1] = (short)f2bf(a.y);
    o[2] = (short)f2bf(a.z); o[3] = (short)f2bf(a.w);
    o[4] = (short)f2bf(b.x); o[5] = (short)f2bf(b.y);
    o[6] = (short)f2bf(b.z); o[7] = (short)f2bf(b.w);
    *(bf16x8*)(pool + i8) = o;
}

// ---------------- ei GEMM + LN + tanh*extra -> bf16 impact -------------------
__global__ __launch_bounds__(256) void gemm_ei(
    const ushort_t* __restrict__ Xb0, const ushort_t* __restrict__ Wb,
    const float* __restrict__ bias, const float* __restrict__ gamma,
    const float* __restrict__ beta, const float* __restrict__ extra,
    ushort_t* __restrict__ outb)
{
    __shared__ float red[32][2][2];
    const int tid = threadIdx.x, wid = tid >> 6, lane = tid & 63;
    const int c2 = lane & 15, g = lane >> 4;
    const int rowblk = wid >> 1, chf = wid & 1, cb0 = chf * 4;
    const int R0 = blockIdx.x * 32 + rowblk * 16;

    f32x4 acc[4] = {};
#pragma unroll
    for (int ch = 0; ch < 4; ch++) {
        const bf16x8 a = *(const bf16x8*)(Xb0 + (size_t)(R0 + c2) * 128 + ch * 32 + g * 8);
#pragma unroll
        for (int j = 0; j < 4; j++) {
            const bf16x8 b = *(const bf16x8*)(Wb + (size_t)((cb0 + j) * 16 + c2) * 128 + ch * 32 + g * 8);
            acc[j] = __builtin_amdgcn_mfma_f32_16x16x32_bf16(a, b, acc[j], 0, 0, 0);
        }
    }
    float gm[4], bt[4];
#pragma unroll
    for (int j = 0; j < 4; j++) {
        const int col = (cb0 + j) * 16 + c2;
        const float bb = bias[col];
        gm[j] = gamma[col]; bt[j] = beta[col];
#pragma unroll
        for (int r = 0; r < 4; r++) acc[j][r] += bb;
    }
#pragma unroll
    for (int r = 0; r < 4; r++) {
        float s = 0.f, ss = 0.f;
#pragma unroll
        for (int j = 0; j < 4; j++) { const float v = acc[j][r]; s += v; ss = fmaf(v, v, ss); }
#pragma unroll
        for (int o = 8; o; o >>= 1) { s += __shfl_xor(s, o); ss += __shfl_xor(ss, o); }
        if (c2 == 0) {
            red[rowblk * 16 + 4 * g + r][chf][0] = s;
            red[rowblk * 16 + 4 * g + r][chf][1] = ss;
        }
    }
    __syncthreads();
#pragma unroll
    for (int r = 0; r < 4; r++) {
        const int lr = rowblk * 16 + 4 * g + r;
        const float S  = red[lr][0][0] + red[lr][1][0];
        const float SS = red[lr][0][1] + red[lr][1][1];
        const float mean = S * (1.0f / 128.0f);
        float var = SS * (1.0f / 128.0f) - mean * mean;
        var = fmaxf(var, 0.0f);
        const float rstd = rsqrtf(var + 1e-5f);
        const int R = blockIdx.x * 32 + lr;
        const float ext = extra[R];
#pragma unroll
        for (int j = 0; j < 4; j++) {
            const float y = (acc[j][r] - mean) * rstd * gm[j] + bt[j];
            outb[(size_t)R * 128 + (cb0 + j) * 16 + c2] = f2bf(tanh_f(y) * ext);
        }
    }
}

// ---------------- fused enh (lobe+tre) + qkv ---------------------------------
__global__ __launch_bounds__(256) void enh_qkv(
    const ushort_t* __restrict__ lobb, const ushort_t* __restrict__ trab,
    const ushort_t* __restrict__ stab,
    const ushort_t* __restrict__ lobw, const ushort_t* __restrict__ trw,
    const ushort_t* __restrict__ ipw, const float* __restrict__ ipb,
    const float* __restrict__ lob_b, const float* __restrict__ lob_g,
    const float* __restrict__ lob_beta,
    const float* __restrict__ tr_b, const float* __restrict__ tr_g,
    const float* __restrict__ tr_beta,
    ushort_t* __restrict__ lobe_b, ushort_t* __restrict__ tre_bf,
    ushort_t* __restrict__ qo, ushort_t* __restrict__ ko, ushort_t* __restrict__ vo)
{
    __shared__ ushort_t lob_t[32][136];
    __shared__ ushort_t tre_t[32][136];
    __shared__ ushort_t vls[128][36];
    __shared__ float red[32][2][4];
    const int tid = threadIdx.x, wid = tid >> 6, lane = tid & 63;
    const int c2 = lane & 15, g = lane >> 4;
    const int rowblk = wid >> 1, chf = wid & 1, cb0 = chf * 4;
    const int RB = blockIdx.x * 32;
    const int R0 = RB + rowblk * 16;

    f32x4 aL[4] = {}, aT[4] = {};
#pragma unroll
    for (int ch = 0; ch < 8; ch++) {
        const int kk = (ch & 3) * 32;
        bf16x8 xl, xt;
        if (ch < 4) {
            xl = *(const bf16x8*)(lobb + (size_t)(R0 + c2) * 128 + kk + g * 8);
            xt = *(const bf16x8*)(trab + (size_t)(R0 + c2) * 128 + kk + g * 8);
        } else {
            xl = *(const bf16x8*)(stab + (size_t)(R0 + c2) * 128 + kk + g * 8);
            xt = xl;
        }
#pragma unroll
        for (int j = 0; j < 4; j++) {
            const size_t wo = (size_t)((cb0 + j) * 16 + c2) * 256 + ch * 32 + g * 8;
            aL[j] = __builtin_amdgcn_mfma_f32_16x16x32_bf16(xl, *(const bf16x8*)(lobw + wo), aL[j], 0, 0, 0);
            aT[j] = __builtin_amdgcn_mfma_f32_16x16x32_bf16(xt, *(const bf16x8*)(trw + wo), aT[j], 0, 0, 0);
        }
    }
#pragma unroll
    for (int j = 0; j < 4; j++) {
        const int col = (cb0 + j) * 16 + c2;
        const float bL = lob_b[col], bT = tr_b[col];
#pragma unroll
        for (int r = 0; r < 4; r++) { aL[j][r] += bL; aT[j][r] += bT; }
    }
#pragma unroll
    for (int r = 0; r < 4; r++) {
        float sL = 0.f, ssL = 0.f, sT = 0.f, ssT = 0.f;
#pragma unroll
        for (int j = 0; j < 4; j++) {
            const float vL = aL[j][r], vT = aT[j][r];
            sL += vL; ssL = fmaf(vL, vL, ssL);
            sT += vT; ssT = fmaf(vT, vT, ssT);
        }
#pragma unroll
        for (int o = 8; o; o >>= 1) {
            sL += __shfl_xor(sL, o); ssL += __shfl_xor(ssL, o);
            sT += __shfl_xor(sT, o); ssT += __shfl_xor(ssT, o);
        }
        if (c2 == 0) {
            float* rd = red[rowblk * 16 + 4 * g + r][chf];
            rd[0] = sL; rd[1] = ssL; rd[2] = sT; rd[3] = ssT;
        }
    }
    __syncthreads();
#pragma unroll
    for (int r = 0; r < 4; r++) {
        const int lr = rowblk * 16 + 4 * g + r;
        const int R = RB + lr;
        const float SL  = red[lr][0][0] + red[lr][1][0];
        const float SSL = red[lr][0][1] + red[lr][1][1];
        const float ST  = red[lr][0][2] + red[lr][1][2];
        const float SST = red[lr][0][3] + red[lr][1][3];
        const float mL = SL * (1.0f / 128.0f), mT = ST * (1.0f / 128.0f);
        const float rL = rsqrtf(fmaxf(SSL * (1.0f / 128.0f) - mL * mL, 0.0f) + 1e-5f);
        const float rT = rsqrtf(fmaxf(SST * (1.0f / 128.0f) - mT * mT, 0.0f) + 1e-5f);
#pragma unroll
        for (int j = 0; j < 4; j++) {
            const int col = (cb0 + j) * 16 + c2;
            const float yL = gelu_f((aL[j][r] - mL) * rL * lob_g[col] + lob_beta[col]);
            const float yT = gelu_f((aT[j][r] - mT) * rT * tr_g[col] + tr_beta[col]);
            const ushort_t lb = f2bf(yL);
            lobe_b[(size_t)R * 128 + col] = lb;
            lob_t[lr][col] = lb;
            const ushort_t tb = f2bf(yT);
            tre_bf[(size_t)R * 128 + col] = tb;
            tre_t[lr][col] = tb;
        }
    }
    __syncthreads();

    const float qscale = 0.17677669529663687f * 1.4426950408889634f;
#pragma unroll
    for (int which = 0; which < 3; which++) {
        const ushort_t (*src)[136] = (which == 0) ? lob_t : tre_t;
        const ushort_t* Wp = ipw + (size_t)which * 16384;
        f32x4 pa[4] = {};
#pragma unroll
        for (int ch = 0; ch < 4; ch++) {
            const bf16x8 a = *(const bf16x8*)&src[rowblk * 16 + c2][ch * 32 + g * 8];
#pragma unroll
            for (int j = 0; j < 4; j++) {
                const bf16x8 b = *(const bf16x8*)(Wp + (size_t)((cb0 + j) * 16 + c2) * 128 + ch * 32 + g * 8);
                pa[j] = __builtin_amdgcn_mfma_f32_16x16x32_bf16(a, b, pa[j], 0, 0, 0);
            }
        }
        if (which < 2) {
            ushort_t* dst = (which == 0) ? qo : ko;
            const float sc = (which == 0) ? qscale : 1.0f;
#pragma unroll
            for (int j = 0; j < 4; j++) {
                const int col = (cb0 + j) * 16 + c2;
                const float bb = ipb[which * 128 + col];
                const int h = col >> 5, hd = col & 31;
#pragma unroll
                for (int r = 0; r < 4; r++) {
                    const int R = R0 + 4 * g + r;
                    const int b = R >> 11, t = R & 2047;
                    dst[(((size_t)b * 4 + h) * 2048 + t) * 32 + hd] = f2bf((pa[j][r] + bb) * sc);
                }
            }
        } else {
#pragma unroll
            for (int j = 0; j < 4; j++) {
                const int col = (cb0 + j) * 16 + c2;
                const float bb = ipb[256 + col];
#pragma unroll
                for (int r = 0; r < 4; r++)
                    vls[col][rowblk * 16 + 4 * g + r] = f2bf(pa[j][r] + bb);
            }
        }
    }
    __syncthreads();
    // V^T global write with kappa permutation (PV B-frag = lane's own words)
    {
        const int col = tid >> 1, hf = tid & 1;
        const int h = col >> 5, hd = col & 31;
        const int b = RB >> 11;
        unsigned w[8];
#pragma unroll
        for (int e = 0; e < 8; e++) {
            const int p0 = hf * 16 + 2 * e;
            const int g2 = p0 >> 3, j2 = p0 & 7;
            const int lk = 4 * g2 + j2 + (j2 >= 4 ? 12 : 0);
            w[e] = (unsigned)vls[col][lk] | ((unsigned)vls[col][lk + 1] << 16);
        }
        ushort_t* dst = vo + (((size_t)b * 4 + h) * 32 + hd) * 2048 + (RB & 2047) + hf * 16;
        *(uint4*)dst       = *(const uint4*)&w[0];
        *(uint4*)(dst + 8) = *(const uint4*)&w[4];
    }
}

// ---------------- flash attention: split-K x2, ctx-layout partials -----------
__global__ __launch_bounds__(256) void attn_kernel(
    const ushort_t* __restrict__ q, const ushort_t* __restrict__ k,
    const ushort_t* __restrict__ vtg,
    ushort_t* __restrict__ part, float* __restrict__ rs_part,
    float* __restrict__ m_part)
{
    __shared__ ushort_t ks[2][64][40];   // K tile   [buf][key][hd]
    __shared__ ushort_t vt[2][32][72];   // V^T tile [buf][d][kappa-pos]
    const int tid = threadIdx.x, wid = tid >> 6, lane = tid & 63;
    const int c = lane & 15, g = lane >> 4;
    const int half = blockIdx.x & 1, qt = blockIdx.x >> 1;
    const int bh = blockIdx.y, b = bh >> 2, h = bh & 3;
    const ushort_t* kb_ = k   + (size_t)bh * 65536 + (size_t)half * 1024 * 32;
    const ushort_t* vb_ = vtg + (size_t)bh * 65536 + (size_t)half * 1024;
    const int q0 = qt * 128 + wid * 32;

    const ushort_t* qbase = q + ((size_t)bh * 2048 + q0) * 32;
    const bf16x8 qf0 = *(const bf16x8*)(qbase + (size_t)c * 32 + g * 8);
    const bf16x8 qf1 = *(const bf16x8*)(qbase + (size_t)(16 + c) * 32 + g * 8);

    bf16x8 ones;
#pragma unroll
    for (int i = 0; i < 8; i++) ones[i] = (short)0x3F80;

    float m0 = 0.0f, m1 = 0.0f;
    f32x4 acc[2][2] = {};
    f32x4 racc[2] = {};

    const int srow = tid >> 2, ssg = tid & 3;  // K staging
    const int vd = tid >> 3, vkg = tid & 7;    // V^T staging

    {
        const bf16x8 kk8 = *(const bf16x8*)(kb_ + (size_t)srow * 32 + ssg * 8);
        const bf16x8 vv8 = *(const bf16x8*)(vb_ + (size_t)vd * 2048 + vkg * 8);
        *(bf16x8*)&ks[0][srow][ssg * 8] = kk8;
        *(bf16x8*)&vt[0][vd][vkg * 8] = vv8;
    }
    __syncthreads();

    for (int kt = 0; kt < 16; kt++) {
        const int cur = kt & 1;
        bf16x8 kk8, vv8;
        if (kt + 1 < 16) {
            kk8 = *(const bf16x8*)(kb_ + ((size_t)(kt + 1) * 64 + srow) * 32 + ssg * 8);
            vv8 = *(const bf16x8*)(vb_ + (size_t)vd * 2048 + (kt + 1) * 64 + vkg * 8);
        }

        // ---- QK^T swapped: C[key][q]; kf shared by both Q frags ----
        f32x4 s0[4], s1[4];
#pragma unroll
        for (int kb2 = 0; kb2 < 4; kb2++) {
            const bf16x8 kf = *(const bf16x8*)&ks[cur][kb2 * 16 + c][g * 8];
            f32x4 z = {};
            s0[kb2] = __builtin_amdgcn_mfma_f32_16x16x32_bf16(kf, qf0, z, 0, 0, 0);
            s1[kb2] = __builtin_amdgcn_mfma_f32_16x16x32_bf16(kf, qf1, z, 0, 0, 0);
        }

        // ---- optimistic softmax: p = exp2(s), packed immediately (m==0
        //      fast path); s preserved for the rare exact slow path. The
        //      exp2 stream has NO dependency on the guard branch below. ----
        union { unsigned u[4]; bf16x8 v; } p0a, p0b, p1a, p1b;
        p0a.u[0] = cvtpk(exp2f(s0[0][0]), exp2f(s0[0][1]));
        p0a.u[1] = cvtpk(exp2f(s0[0][2]), exp2f(s0[0][3]));
        p0a.u[2] = cvtpk(exp2f(s0[1][0]), exp2f(s0[1][1]));
        p0a.u[3] = cvtpk(exp2f(s0[1][2]), exp2f(s0[1][3]));
        p0b.u[0] = cvtpk(exp2f(s0[2][0]), exp2f(s0[2][1]));
        p0b.u[1] = cvtpk(exp2f(s0[2][2]), exp2f(s0[2][3]));
        p0b.u[2] = cvtpk(exp2f(s0[3][0]), exp2f(s0[3][1]));
        p0b.u[3] = cvtpk(exp2f(s0[3][2]), exp2f(s0[3][3]));
        p1a.u[0] = cvtpk(exp2f(s1[0][0]), exp2f(s1[0][1]));
        p1a.u[1] = cvtpk(exp2f(s1[0][2]), exp2f(s1[0][3]));
        p1a.u[2] = cvtpk(exp2f(s1[1][0]), exp2f(s1[1][1]));
        p1a.u[3] = cvtpk(exp2f(s1[1][2]), exp2f(s1[1][3]));
        p1b.u[0] = cvtpk(exp2f(s1[2][0]), exp2f(s1[2][1]));
        p1b.u[1] = cvtpk(exp2f(s1[2][2]), exp2f(s1[2][3]));
        p1b.u[2] = cvtpk(exp2f(s1[3][0]), exp2f(s1[3][1]));
        p1b.u[3] = cvtpk(exp2f(s1[3][2]), exp2f(s1[3][3]));

        // ---- guard (runs in parallel with the exp2 stream above) ----
        float lm = MX3(s0[0][0], s0[0][1], s0[0][2]);
        lm = MX3(lm, s0[0][3], s0[1][0]);
        lm = MX3(lm, s0[1][1], s0[1][2]);
        lm = MX3(lm, s0[1][3], s0[2][0]);
        lm = MX3(lm, s0[2][1], s0[2][2]);
        lm = MX3(lm, s0[2][3], s0[3][0]);
        lm = MX3(lm, s0[3][1], s0[3][2]);
        lm = MX3(lm, s0[3][3], s1[0][0]);
        lm = MX3(lm, s1[0][1], s1[0][2]);
        lm = MX3(lm, s1[0][3], s1[1][0]);
        lm = MX3(lm, s1[1][1], s1[1][2]);
        lm = MX3(lm, s1[1][3], s1[2][0]);
        lm = MX3(lm, s1[2][1], s1[2][2]);
        lm = MX3(lm, s1[2][3], s1[3][0]);
        lm = MX3(lm, s1[3][1], s1[3][2]);
        lm = fmaxf(lm, s1[3][3]);
        if (__any(lm > 80.0f || m0 != 0.0f || m1 != 0.0f)) {
            // exact online-softmax slow path (rare; s still live)
            float l0 = -1e30f, l1 = -1e30f;
#pragma unroll
            for (int kb2 = 0; kb2 < 4; kb2++) {
#pragma unroll
                for (int r = 0; r < 4; r++) { l0 = fmaxf(l0, s0[kb2][r]); l1 = fmaxf(l1, s1[kb2][r]); }
            }
            l0 = fmaxf(l0, __shfl_xor(l0, 16)); l0 = fmaxf(l0, __shfl_xor(l0, 32));
            l1 = fmaxf(l1, __shfl_xor(l1, 16)); l1 = fmaxf(l1, __shfl_xor(l1, 32));
            const float n0 = fmaxf(m0, l0), n1 = fmaxf(m1, l1);
            const float a0 = exp2f(m0 - n0), a1 = exp2f(m1 - n1);
#pragma unroll
            for (int nb = 0; nb < 2; nb++)
#pragma unroll
                for (int r = 0; r < 4; r++) { acc[0][nb][r] *= a0; acc[1][nb][r] *= a1; }
#pragma unroll
            for (int r = 0; r < 4; r++) { racc[0][r] *= a0; racc[1][r] *= a1; }
            m0 = n0; m1 = n1;
            p0a.u[0] = cvtpk(exp2f(s0[0][0] - m0), exp2f(s0[0][1] - m0));
            p0a.u[1] = cvtpk(exp2f(s0[0][2] - m0), exp2f(s0[0][3] - m0));
            p0a.u[2] = cvtpk(exp2f(s0[1][0] - m0), exp2f(s0[1][1] - m0));
            p0a.u[3] = cvtpk(exp2f(s0[1][2] - m0), exp2f(s0[1][3] - m0));
            p0b.u[0] = cvtpk(exp2f(s0[2][0] - m0), exp2f(s0[2][1] - m0));
            p0b.u[1] = cvtpk(exp2f(s0[2][2] - m0), exp2f(s0[2][3] - m0));
            p0b.u[2] = cvtpk(exp2f(s0[3][0] - m0), exp2f(s0[3][1] - m0));
            p0b.u[3] = cvtpk(exp2f(s0[3][2] - m0), exp2f(s0[3][3] - m0));
            p1a.u[0] = cvtpk(exp2f(s1[0][0] - m1), exp2f(s1[0][1] - m1));
            p1a.u[1] = cvtpk(exp2f(s1[0][2] - m1), exp2f(s1[0][3] - m1));
            p1a.u[2] = cvtpk(exp2f(s1[1][0] - m1), exp2f(s1[1][1] - m1));
            p1a.u[3] = cvtpk(exp2f(s1[1][2] - m1), exp2f(s1[1][3] - m1));
            p1b.u[0] = cvtpk(exp2f(s1[2][0] - m1), exp2f(s1[2][1] - m1));
            p1b.u[1] = cvtpk(exp2f(s1[2][2] - m1), exp2f(s1[2][3] - m1));
            p1b.u[2] = cvtpk(exp2f(s1[3][0] - m1), exp2f(s1[3][1] - m1));
            p1b.u[3] = cvtpk(exp2f(s1[3][2] - m1), exp2f(s1[3][3] - m1));
        }

        // ---- PV + denominator (all on matrix pipe) ----
#pragma unroll
        for (int nb = 0; nb < 2; nb++) {
            const bf16x8 v0 = *(const bf16x8*)&vt[cur][nb * 16 + c][g * 8];
            const bf16x8 v1 = *(const bf16x8*)&vt[cur][nb * 16 + c][32 + g * 8];
            acc[0][nb] = __builtin_amdgcn_mfma_f32_16x16x32_bf16(v0, p0a.v, acc[0][nb], 0, 0, 0);
            acc[0][nb] = __builtin_amdgcn_mfma_f32_16x16x32_bf16(v1, p0b.v, acc[0][nb], 0, 0, 0);
            acc[1][nb] = __builtin_amdgcn_mfma_f32_16x16x32_bf16(v0, p1a.v, acc[1][nb], 0, 0, 0);
            acc[1][nb] = __builtin_amdgcn_mfma_f32_16x16x32_bf16(v1, p1b.v, acc[1][nb], 0, 0, 0);
        }
        racc[0] = __builtin_amdgcn_mfma_f32_16x16x32_bf16(ones, p0a.v, racc[0], 0, 0, 0);
        racc[0] = __builtin_amdgcn_mfma_f32_16x16x32_bf16(ones, p0b.v, racc[0], 0, 0, 0);
        racc[1] = __builtin_amdgcn_mfma_f32_16x16x32_bf16(ones, p1a.v, racc[1], 0, 0, 0);
        racc[1] = __builtin_amdgcn_mfma_f32_16x16x32_bf16(ones, p1b.v, racc[1], 0, 0, 0);

        if (kt + 1 < 16) {
            *(bf16x8*)&ks[cur ^ 1][srow][ssg * 8] = kk8;
            *(bf16x8*)&vt[cur ^ 1][vd][vkg * 8] = vv8;
        }
        __syncthreads();
    }

    // ---- partial store in ctx layout: part[half][b][t][h*32+d] (uint2) ------
    ushort_t* pb = part + (size_t)half * 2097152;
#pragma unroll
    for (int qf = 0; qf < 2; qf++) {
        const int qrow = q0 + qf * 16 + c;
        ushort_t* dst = pb + ((size_t)(b * 2048 + qrow)) * 128 + h * 32;
#pragma unroll
        for (int nb = 0; nb < 2; nb++) {
            uint2 wv;
            wv.x = cvtpk(acc[qf][nb][0], acc[qf][nb][1]);
            wv.y = cvtpk(acc[qf][nb][2], acc[qf][nb][3]);
            *(uint2*)(dst + nb * 16 + 4 * g) = wv;
        }
    }
    if (g == 0) {
        float* rsp = rs_part + (size_t)(half * 32 + bh) * 2048;
        float* mp  = m_part  + (size_t)(half * 32 + bh) * 2048;
        rsp[q0 + c]      = racc[0][0];
        rsp[q0 + 16 + c] = racc[1][0];
        mp[q0 + c]       = m0;
        mp[q0 + 16 + c]  = m1;
    }
}

// ------- fused split-K combine + out-proj + residual-LN + final GEMM ---------
__global__ __launch_bounds__(256) void out_fuse(
    const ushort_t* __restrict__ ctxA, const ushort_t* __restrict__ ctxB,
    const float* __restrict__ rs_part, const float* __restrict__ m_part,
    const ushort_t* __restrict__ treb,
    const ushort_t* __restrict__ opw, const float* __restrict__ opb,
    const float* __restrict__ cn_g, const float* __restrict__ cn_b,
    const ushort_t* __restrict__ ofw, const float* __restrict__ of_b,
    const float* __restrict__ of_g, const float* __restrict__ of_beta,
    const ushort_t* __restrict__ lobe_b, float* __restrict__ out)
{
    __shared__ ushort_t fus_t[32][136];
    __shared__ float red[32][2][2];
    const int tid = threadIdx.x, wid = tid >> 6, lane = tid & 63;
    const int c2 = lane & 15, g = lane >> 4;
    const int rowblk = wid >> 1, chf = wid & 1, cb0 = chf * 4;
    const int RB = blockIdx.x * 32;
    const int R0 = RB + rowblk * 16;

    // ---- per-lane-row, per-head combine factors ----
    const int rowA = R0 + c2;
    const int bb2 = rowA >> 11, tt = rowA & 2047;
    float fA[4], fB[4];
#pragma unroll
    for (int h = 0; h < 4; h++) {
        const int bh = bb2 * 4 + h;
        const float mA = m_part[(size_t)bh * 2048 + tt];
        const float mB = m_part[(size_t)(32 + bh) * 2048 + tt];
        const float rA = rs_part[(size_t)bh * 2048 + tt];
        const float rB = rs_part[(size_t)(32 + bh) * 2048 + tt];
        const float M = fmaxf(mA, mB);
        const float wA = exp2f(mA - M), wB = exp2f(mB - M);
        const float inv = __builtin_amdgcn_rcpf(fmaf(rA, wA, rB * wB));
        fA[h] = wA * inv; fB[h] = wB * inv;
    }

    // ---- phase A: fused = LN(lobe + combined_ctx @ opw + opb) ----
    f32x4 acc[4] = {};
#pragma unroll
    for (int ch = 0; ch < 4; ch++) {
        const bf16x8 aA = *(const bf16x8*)(ctxA + (size_t)rowA * 128 + ch * 32 + g * 8);
        const bf16x8 aB = *(const bf16x8*)(ctxB + (size_t)rowA * 128 + ch * 32 + g * 8);
        union { unsigned u[4]; bf16x8 v; } am;
#pragma unroll
        for (int i = 0; i < 4; i++) {
            const float e0 = bf2f((ushort_t)aA[2 * i]) * fA[ch] + bf2f((ushort_t)aB[2 * i]) * fB[ch];
            const float e1 = bf2f((ushort_t)aA[2 * i + 1]) * fA[ch] + bf2f((ushort_t)aB[2 * i + 1]) * fB[ch];
            am.u[i] = cvtpk(e0, e1);
        }
#pragma unroll
        for (int j = 0; j < 4; j++) {
            const bf16x8 b = *(const bf16x8*)(opw + (size_t)((cb0 + j) * 16 + c2) * 128 + ch * 32 + g * 8);
            acc[j] = __builtin_amdgcn_mfma_f32_16x16x32_bf16(am.v, b, acc[j], 0, 0, 0);
        }
    }
#pragma unroll
    for (int j = 0; j < 4; j++) {
        const int col = (cb0 + j) * 16 + c2;
        const float bb = opb[col];
#pragma unroll
        for (int r = 0; r < 4; r++)
            acc[j][r] += bb + bf2f(lobe_b[(size_t)(R0 + 4 * g + r) * 128 + col]);
    }
#pragma unroll
    for (int r = 0; r < 4; r++) {
        float s = 0.f, ss = 0.f;
#pragma unroll
        for (int j = 0; j < 4; j++) { const float v = acc[j][r]; s += v; ss = fmaf(v, v, ss); }
#pragma unroll
        for (int o = 8; o; o >>= 1) { s += __shfl_xor(s, o); ss += __shfl_xor(ss, o); }
        if (c2 == 0) {
            red[rowblk * 16 + 4 * g + r][chf][0] = s;
            red[rowblk * 16 + 4 * g + r][chf][1] = ss;
        }
    }
    __syncthreads();
#pragma unroll
    for (int r = 0; r < 4; r++) {
        const int lr = rowblk * 16 + 4 * g + r;
        const float S  = red[lr][0][0] + red[lr][1][0];
        const float SS = red[lr][0][1] + red[lr][1][1];
        const float mean = S * (1.0f / 128.0f);
        const float rstd = rsqrtf(fmaxf(SS * (1.0f / 128.0f) - mean * mean, 0.0f) + 1e-5f);
#pragma unroll
        for (int j = 0; j < 4; j++) {
            const int col = (cb0 + j) * 16 + c2;
            fus_t[lr][col] = f2bf((acc[j][r] - mean) * rstd * cn_g[col] + cn_b[col]);
        }
    }
    __syncthreads();

    // ---- phase B: out = gelu(LN([fused, tre]@ofw + ofb)) ----
    f32x4 a2[4] = {};
#pragma unroll
    for (int ch = 0; ch < 8; ch++) {
        bf16x8 a;
        if (ch < 4) a = *(const bf16x8*)&fus_t[rowblk * 16 + c2][ch * 32 + g * 8];
        else        a = *(const bf16x8*)(treb + (size_t)(R0 + c2) * 128 + (ch - 4) * 32 + g * 8);
#pragma unroll
        for (int j = 0; j < 4; j++) {
            const bf16x8 b = *(const bf16x8*)(ofw + (size_t)((cb0 + j) * 16 + c2) * 256 + ch * 32 + g * 8);
            a2[j] = __builtin_amdgcn_mfma_f32_16x16x32_bf16(a, b, a2[j], 0, 0, 0);
        }
    }
#pragma unroll
    for (int j = 0; j < 4; j++) {
        const float bb = of_b[(cb0 + j) * 16 + c2];
#pragma unroll
        for (int r = 0; r < 4; r++) a2[j][r] += bb;
    }
#pragma unroll
    for (int r = 0; r < 4; r++) {
        float s = 0.f, ss = 0.f;
#pragma unroll
        for (int j = 0; j < 4; j++) { const float v = a2[j][r]; s += v; ss = fmaf(v, v, ss); }
#pragma unroll
        for (int o = 8; o; o >>= 1) { s += __shfl_xor(s, o); ss += __shfl_xor(ss, o); }
        if (c2 == 0) {
            red[rowblk * 16 + 4 * g + r][chf][0] = s;
            red[rowblk * 16 + 4 * g + r][chf][1] = ss;
        }
    }
    __syncthreads();
#pragma unroll
    for (int r = 0; r < 4; r++) {
        const int lr = rowblk * 16 + 4 * g + r;
        const float S  = red[lr][0][0] + red[lr][1][0];
        const float SS = red[lr][0][1] + red[lr][1][1];
        const float mean = S * (1.0f / 128.0f);
        const float rstd = rsqrtf(fmaxf(SS * (1.0f / 128.0f) - mean * mean, 0.0f) + 1e-5f);
        const int R = RB + lr;
#pragma unroll
        for (int j = 0; j < 4; j++) {
            const int col = (cb0 + j) * 16 + c2;
            const float y = (a2[j][r] - mean) * rstd * of_g[col] + of_beta[col];
            out[(size_t)R * 128 + col] = gelu_f(y);
        }
    }
}

// ---------------- decay scan: ends -> carry -> re-scan -----------------------
__global__ void scan_ends_kernel(const ushort_t* __restrict__ imp,
                                 const float* __restrict__ decay,
                                 float* __restrict__ ends)
{
    const int c = threadIdx.x;
    const int ch = blockIdx.x, b = blockIdx.y;
    const float d = sigm(decay[c]);
    const size_t base = ((size_t)b * T_ + ch * 64) * 128 + c;
    float s = 0.0f;
#pragma unroll 4
    for (int tl = 0; tl < 64; tl++)
        s = fmaf(d, s, bf2f(imp[base + (size_t)tl * 128]));
    ends[((size_t)b * 32 + ch) * 128 + c] = s;
}

__global__ void scan_carry_kernel(const float* __restrict__ ends,
                                  const float* __restrict__ decay,
                                  float* __restrict__ carry)
{
    const int c = threadIdx.x;
    const int b = blockIdx.x;
    const float d = sigm(decay[c]);
    float dl = d;
#pragma unroll
    for (int i = 0; i < 6; i++) dl *= dl;  // d^64
    float e = 0.0f;
#pragma unroll
    for (int ch = 0; ch < 32; ch++) {
        carry[((size_t)b * 32 + ch) * 128 + c] = e;
        e = fmaf(dl, e, ends[((size_t)b * 32 + ch) * 128 + c]);
    }
}

__global__ void scan_fin_kernel(const ushort_t* __restrict__ imp,
                                const float* __restrict__ decay,
                                const float* __restrict__ carry,
                                ushort_t* __restrict__ stbf)
{
    const int c = threadIdx.x;
    const int ch = blockIdx.x, b = blockIdx.y;
    const float d = sigm(decay[c]);
    float s = carry[((size_t)b * 32 + ch) * 128 + c];
    const size_t base = ((size_t)b * T_ + ch * 64) * 128 + c;
#pragma unroll 4
    for (int tl = 0; tl < 64; tl++) {
        s = fmaf(d, s, bf2f(imp[base + (size_t)tl * 128]));
        stbf[base + (size_t)tl * 128] = f2bf(s);
    }
}

extern "C" void kernel_launch(void* const* d_in, const int* in_sizes, int n_in,
                              void* d_out, int out_size, void* d_ws, size_t ws_size,
                              hipStream_t stream)
{
    const float* lob_feat   = (const float*)d_in[0];
    const float* trade_feat = (const float*)d_in[1];
    const float* has_trade  = (const float*)d_in[2];
    const float* ei_w       = (const float*)d_in[3];
    const float* ei_b       = (const float*)d_in[4];
    const float* ei_g       = (const float*)d_in[5];
    const float* ei_beta    = (const float*)d_in[6];
    const float* decay      = (const float*)d_in[7];
    const float* in_proj_w  = (const float*)d_in[8];
    const float* in_proj_b  = (const float*)d_in[9];
    const float* out_proj_w = (const float*)d_in[10];
    const float* out_proj_b = (const float*)d_in[11];
    const float* cn_g       = (const float*)d_in[12];
    const float* cn_b       = (const float*)d_in[13];
    const float* lob_w      = (const float*)d_in[14];
    const float* lob_b      = (const float*)d_in[15];
    const float* lob_g      = (const float*)d_in[16];
    const float* lob_beta   = (const float*)d_in[17];
    const float* tr_w       = (const float*)d_in[18];
    const float* tr_b       = (const float*)d_in[19];
    const float* tr_g       = (const float*)d_in[20];
    const float* tr_beta    = (const float*)d_in[21];
    const float* of_w       = (const float*)d_in[22];
    const float* of_b       = (const float*)d_in[23];
    const float* of_g       = (const float*)d_in[24];
    const float* of_beta    = (const float*)d_in[25];

    char* W = (char*)d_ws;
    const size_t MB = 1u << 20;
    ushort_t* lobe_b   = (ushort_t*)W;               // 0-4 MB
    float*    carry    = (float*)(W + 8 * MB);
    float*    ends     = (float*)(W + 8 * MB + 256 * 1024);
    ushort_t* pool     = (ushort_t*)(W + 9 * MB);    // 9-17.75 MB
    ushort_t* imp_bf   = (ushort_t*)(W + 18 * MB);   // 18-22
    ushort_t* state_bf = (ushort_t*)(W + 22 * MB);
    ushort_t* tre_bf   = (ushort_t*)(W + 26 * MB);
    ushort_t* q_bf     = (ushort_t*)(W + 30 * MB);
    ushort_t* k_bf     = (ushort_t*)(W + 34 * MB);
    ushort_t* vt_g     = (ushort_t*)(W + 38 * MB);
    ushort_t* part     = (ushort_t*)(W + 42 * MB);   // 2 x 4 MB ctx partials
    float*    rs_part  = (float*)(W + 50 * MB);      // 512 KB
    float*    m_part   = (float*)(W + 50 * MB + 512 * 1024);

    ushort_t* lob_bf   = pool;
    ushort_t* trade_bf = pool + 2097152;
    ushort_t* eiw_bf   = pool + 4194304;
    ushort_t* ipw_bf   = pool + 4210688;
    ushort_t* opw_bf   = pool + 4259840;
    ushort_t* lobw_bf  = pool + 4276224;
    ushort_t* trw_bf   = pool + 4308992;
    ushort_t* ofw_bf   = pool + 4341760;

    ushort_t* ctxA = part;
    ushort_t* ctxB = part + 2097152;

    const dim3 blk(256);

    prep_kernel<<<dim3(2136), blk, 0, stream>>>(lob_feat, trade_feat, ei_w, in_proj_w,
                                                out_proj_w, lob_w, tr_w, of_w, pool);
    gemm_ei<<<dim3(512), blk, 0, stream>>>(trade_bf, eiw_bf, ei_b, ei_g, ei_beta,
                                           has_trade, imp_bf);
    scan_ends_kernel<<<dim3(32, 8), dim3(128), 0, stream>>>(imp_bf, decay, ends);
    scan_carry_kernel<<<dim3(8), dim3(128), 0, stream>>>(ends, decay, carry);
    scan_fin_kernel<<<dim3(32, 8), dim3(128), 0, stream>>>(imp_bf, decay, carry, state_bf);
    enh_qkv<<<dim3(512), blk, 0, stream>>>(lob_bf, trade_bf, state_bf, lobw_bf, trw_bf,
                                           ipw_bf, in_proj_b, lob_b, lob_g, lob_beta,
                                           tr_b, tr_g, tr_beta, lobe_b, tre_bf,
                                           q_bf, k_bf, vt_g);
    attn_kernel<<<dim3(32, 32), blk, 0, stream>>>(q_bf, k_bf, vt_g, part, rs_part, m_part);
    out_fuse<<<dim3(512), blk, 0, stream>>>(ctxA, ctxB, rs_part, m_part, tre_bf,
                                            opw_bf, out_proj_b, cn_g, cn_b,
                                            ofw_bf, of_b, of_g, of_beta, lobe_b, (float*)d_out);
}

// Round 16
// 131.683 us; speedup vs baseline: 1.0782x; 1.0060x over previous
//
#include <hip/hip_runtime.h>
#include <math.h>

// B=8, T=2048, D=128, NH=4, HD=32. BT=16384 rows.
// Round 16: r15 (best verified, 132.47us) + adoption of the r10/r11-validated
// front-end: prep converts WEIGHTS ONLY (88 blocks); lob/trade converted
// inline (v_cvt_pk) in consumers; gemm_ei+scan_ends fused into ei_scan
// (64-row blocks, 512 thr, twice correctness-validated). attn/out_fuse are
// byte-identical to r15. 7 dispatches.

#define T_  2048

typedef short bf16x8 __attribute__((ext_vector_type(8)));
typedef float f32x4  __attribute__((ext_vector_type(4)));
typedef unsigned short ushort_t;

__device__ __forceinline__ float sigm(float x) { return 1.0f / (1.0f + __expf(-x)); }

__device__ __forceinline__ unsigned short f2bf(float x) {
    union { float f; unsigned u; } v; v.f = x;
    unsigned r = v.u + 0x7FFFu + ((v.u >> 16) & 1u);  // RNE
    return (unsigned short)(r >> 16);
}
__device__ __forceinline__ float bf2f(ushort_t u) {
    union { unsigned u; float f; } v; v.u = ((unsigned)u) << 16; return v.f;
}
__device__ __forceinline__ unsigned cvtpk(float a, float b) {
    unsigned r;
    asm("v_cvt_pk_bf16_f32 %0, %1, %2" : "=v"(r) : "v"(a), "v"(b));
    return r;
}
// load 8 f32 -> bf16x8 via cvt_pk (validated r10/r11, absmax unchanged)
__device__ __forceinline__ bf16x8 ld_f32_bf8(const float* p) {
    const float4 a = *(const float4*)p;
    const float4 b = *(const float4*)(p + 4);
    union { unsigned u[4]; bf16x8 v; } o;
    o.u[0] = cvtpk(a.x, a.y); o.u[1] = cvtpk(a.z, a.w);
    o.u[2] = cvtpk(b.x, b.y); o.u[3] = cvtpk(b.z, b.w);
    return o.v;
}

__device__ __forceinline__ float gelu_f(float x) {
    const float e = exp2f(fmaf(0.044715f * x, x * x, x) * -2.3022083f);
    return x * __builtin_amdgcn_rcpf(1.0f + e);
}
__device__ __forceinline__ float tanh_f(float y) {
    const float e = exp2f(y * 2.8853900818f);
    return 1.0f - 2.0f * __builtin_amdgcn_rcpf(e + 1.0f);
}
#define MX3(a, b, c) fmaxf(fmaxf((a), (b)), (c))

// ---------------- prep: weights only -> bf16 pool ----------------------------
// elems: eiw 0, ipw 16384, opw 65536, lobw 81920, trw 114688, ofw 147456..180224
__global__ __launch_bounds__(256) void prep_w(
    const float* __restrict__ eiw, const float* __restrict__ ipw,
    const float* __restrict__ opw, const float* __restrict__ lobw,
    const float* __restrict__ trw, const float* __restrict__ ofw,
    ushort_t* __restrict__ pool)
{
    const size_t i8 = ((size_t)blockIdx.x * 256 + threadIdx.x) * 8;
    const float* src; size_t off;
    if      (i8 < 16384)  { src = eiw;  off = 0; }
    else if (i8 < 65536)  { src = ipw;  off = 16384; }
    else if (i8 < 81920)  { src = opw;  off = 65536; }
    else if (i8 < 114688) { src = lobw; off = 81920; }
    else if (i8 < 147456) { src = trw;  off = 114688; }
    else                  { src = ofw;  off = 147456; }
    *(bf16x8*)(pool + i8) = ld_f32_bf8(src + (i8 - off));
}

// ------- ei GEMM (f32 in, inline cvt) + LN + tanh*extra + fused ends-scan ----
// 512 thr, 64 rows/block, grid 256. Phase B: threads 0..127 scan the LDS tile.
__global__ __launch_bounds__(512) void ei_scan(
    const float* __restrict__ trade, const ushort_t* __restrict__ Wb,
    const float* __restrict__ bias, const float* __restrict__ gamma,
    const float* __restrict__ beta, const float* __restrict__ extra,
    const float* __restrict__ decay,
    ushort_t* __restrict__ imp_out, float* __restrict__ ends)
{
    __shared__ ushort_t imp_t[64][132];
    __shared__ float red[64][2][2];
    const int tid = threadIdx.x, wid = tid >> 6, lane = tid & 63;
    const int c2 = lane & 15, g = lane >> 4;
    const int rowblk = wid >> 1, chf = wid & 1, cb0 = chf * 4;
    const int RB = blockIdx.x * 64;
    const int R0 = RB + rowblk * 16;

    f32x4 acc[4] = {};
#pragma unroll
    for (int ch = 0; ch < 4; ch++) {
        const bf16x8 a = ld_f32_bf8(trade + (size_t)(R0 + c2) * 128 + ch * 32 + g * 8);
#pragma unroll
        for (int j = 0; j < 4; j++) {
            const bf16x8 b = *(const bf16x8*)(Wb + (size_t)((cb0 + j) * 16 + c2) * 128 + ch * 32 + g * 8);
            acc[j] = __builtin_amdgcn_mfma_f32_16x16x32_bf16(a, b, acc[j], 0, 0, 0);
        }
    }
    float gm[4], bt[4];
#pragma unroll
    for (int j = 0; j < 4; j++) {
        const int col = (cb0 + j) * 16 + c2;
        const float bb = bias[col];
        gm[j] = gamma[col]; bt[j] = beta[col];
#pragma unroll
        for (int r = 0; r < 4; r++) acc[j][r] += bb;
    }
#pragma unroll
    for (int r = 0; r < 4; r++) {
        float s = 0.f, ss = 0.f;
#pragma unroll
        for (int j = 0; j < 4; j++) { const float v = acc[j][r]; s += v; ss = fmaf(v, v, ss); }
#pragma unroll
        for (int o = 8; o; o >>= 1) { s += __shfl_xor(s, o); ss += __shfl_xor(ss, o); }
        if (c2 == 0) {
            red[rowblk * 16 + 4 * g + r][chf][0] = s;
            red[rowblk * 16 + 4 * g + r][chf][1] = ss;
        }
    }
    __syncthreads();
#pragma unroll
    for (int r = 0; r < 4; r++) {
        const int lr = rowblk * 16 + 4 * g + r;
        const float S  = red[lr][0][0] + red[lr][1][0];
        const float SS = red[lr][0][1] + red[lr][1][1];
        const float mean = S * (1.0f / 128.0f);
        const float rstd = rsqrtf(fmaxf(SS * (1.0f / 128.0f) - mean * mean, 0.0f) + 1e-5f);
        const int R = RB + lr;
        const float ext = extra[R];
#pragma unroll
        for (int j = 0; j < 4; j++) {
            const int col = (cb0 + j) * 16 + c2;
            const float y = (acc[j][r] - mean) * rstd * gm[j] + bt[j];
            const ushort_t ib = f2bf(tanh_f(y) * ext);
            imp_out[(size_t)R * 128 + col] = ib;
            imp_t[lr][col] = ib;
        }
    }
    __syncthreads();
    if (tid < 128) {
        const int c = tid;
        const float d = sigm(decay[c]);
        float s = 0.0f;
#pragma unroll 4
        for (int tl = 0; tl < 64; tl++) s = fmaf(d, s, bf2f(imp_t[tl][c]));
        const int b = RB >> 11, ch64 = (RB & 2047) >> 6;
        ends[((size_t)b * 32 + ch64) * 128 + c] = s;
    }
}

// ---------------- fused enh (lobe+tre, f32 inputs) + qkv ---------------------
__global__ __launch_bounds__(256) void enh_qkv(
    const float* __restrict__ lobf, const float* __restrict__ traf,
    const ushort_t* __restrict__ stab,
    const ushort_t* __restrict__ lobw, const ushort_t* __restrict__ trw,
    const ushort_t* __restrict__ ipw, const float* __restrict__ ipb,
    const float* __restrict__ lob_b, const float* __restrict__ lob_g,
    const float* __restrict__ lob_beta,
    const float* __restrict__ tr_b, const float* __restrict__ tr_g,
    const float* __restrict__ tr_beta,
    ushort_t* __restrict__ lobe_b, ushort_t* __restrict__ tre_bf,
    ushort_t* __restrict__ qo, ushort_t* __restrict__ ko, ushort_t* __restrict__ vo)
{
    __shared__ ushort_t lob_t[32][136];
    __shared__ ushort_t tre_t[32][136];
    __shared__ ushort_t vls[128][36];
    __shared__ float red[32][2][4];
    const int tid = threadIdx.x, wid = tid >> 6, lane = tid & 63;
    const int c2 = lane & 15, g = lane >> 4;
    const int rowblk = wid >> 1, chf = wid & 1, cb0 = chf * 4;
    const int RB = blockIdx.x * 32;
    const int R0 = RB + rowblk * 16;

    f32x4 aL[4] = {}, aT[4] = {};
#pragma unroll
    for (int ch = 0; ch < 8; ch++) {
        const int kk = (ch & 3) * 32;
        bf16x8 xl, xt;
        if (ch < 4) {
            xl = ld_f32_bf8(lobf + (size_t)(R0 + c2) * 128 + kk + g * 8);
            xt = ld_f32_bf8(traf + (size_t)(R0 + c2) * 128 + kk + g * 8);
        } else {
            xl = *(const bf16x8*)(stab + (size_t)(R0 + c2) * 128 + kk + g * 8);
            xt = xl;
        }
#pragma unroll
        for (int j = 0; j < 4; j++) {
            const size_t wo = (size_t)((cb0 + j) * 16 + c2) * 256 + ch * 32 + g * 8;
            aL[j] = __builtin_amdgcn_mfma_f32_16x16x32_bf16(xl, *(const bf16x8*)(lobw + wo), aL[j], 0, 0, 0);
            aT[j] = __builtin_amdgcn_mfma_f32_16x16x32_bf16(xt, *(const bf16x8*)(trw + wo), aT[j], 0, 0, 0);
        }
    }
#pragma unroll
    for (int j = 0; j < 4; j++) {
        const int col = (cb0 + j) * 16 + c2;
        const float bL = lob_b[col], bT = tr_b[col];
#pragma unroll
        for (int r = 0; r < 4; r++) { aL[j][r] += bL; aT[j][r] += bT; }
    }
#pragma unroll
    for (int r = 0; r < 4; r++) {
        float sL = 0.f, ssL = 0.f, sT = 0.f, ssT = 0.f;
#pragma unroll
        for (int j = 0; j < 4; j++) {
            const float vL = aL[j][r], vT = aT[j][r];
            sL += vL; ssL = fmaf(vL, vL, ssL);
            sT += vT; ssT = fmaf(vT, vT, ssT);
        }
#pragma unroll
        for (int o = 8; o; o >>= 1) {
            sL += __shfl_xor(sL, o); ssL += __shfl_xor(ssL, o);
            sT += __shfl_xor(sT, o); ssT += __shfl_xor(ssT, o);
        }
        if (c2 == 0) {
            float* rd = red[rowblk * 16 + 4 * g + r][chf];
            rd[0] = sL; rd[1] = ssL; rd[2] = sT; rd[3] = ssT;
        }
    }
    __syncthreads();
#pragma unroll
    for (int r = 0; r < 4; r++) {
        const int lr = rowblk * 16 + 4 * g + r;
        const int R = RB + lr;
        const float SL  = red[lr][0][0] + red[lr][1][0];
        const float SSL = red[lr][0][1] + red[lr][1][1];
        const float ST  = red[lr][0][2] + red[lr][1][2];
        const float SST = red[lr][0][3] + red[lr][1][3];
        const float mL = SL * (1.0f / 128.0f), mT = ST * (1.0f / 128.0f);
        const float rL = rsqrtf(fmaxf(SSL * (1.0f / 128.0f) - mL * mL, 0.0f) + 1e-5f);
        const float rT = rsqrtf(fmaxf(SST * (1.0f / 128.0f) - mT * mT, 0.0f) + 1e-5f);
#pragma unroll
        for (int j = 0; j < 4; j++) {
            const int col = (cb0 + j) * 16 + c2;
            const float yL = gelu_f((aL[j][r] - mL) * rL * lob_g[col] + lob_beta[col]);
            const float yT = gelu_f((aT[j][r] - mT) * rT * tr_g[col] + tr_beta[col]);
            const ushort_t lb = f2bf(yL);
            lobe_b[(size_t)R * 128 + col] = lb;
            lob_t[lr][col] = lb;
            const ushort_t tb = f2bf(yT);
            tre_bf[(size_t)R * 128 + col] = tb;
            tre_t[lr][col] = tb;
        }
    }
    __syncthreads();

    const float qscale = 0.17677669529663687f * 1.4426950408889634f;
#pragma unroll
    for (int which = 0; which < 3; which++) {
        const ushort_t (*src)[136] = (which == 0) ? lob_t : tre_t;
        const ushort_t* Wp = ipw + (size_t)which * 16384;
        f32x4 pa[4] = {};
#pragma unroll
        for (int ch = 0; ch < 4; ch++) {
            const bf16x8 a = *(const bf16x8*)&src[rowblk * 16 + c2][ch * 32 + g * 8];
#pragma unroll
            for (int j = 0; j < 4; j++) {
                const bf16x8 b = *(const bf16x8*)(Wp + (size_t)((cb0 + j) * 16 + c2) * 128 + ch * 32 + g * 8);
                pa[j] = __builtin_amdgcn_mfma_f32_16x16x32_bf16(a, b, pa[j], 0, 0, 0);
            }
        }
        if (which < 2) {
            ushort_t* dst = (which == 0) ? qo : ko;
            const float sc = (which == 0) ? qscale : 1.0f;
#pragma unroll
            for (int j = 0; j < 4; j++) {
                const int col = (cb0 + j) * 16 + c2;
                const float bb = ipb[which * 128 + col];
                const int h = col >> 5, hd = col & 31;
#pragma unroll
                for (int r = 0; r < 4; r++) {
                    const int R = R0 + 4 * g + r;
                    const int b = R >> 11, t = R & 2047;
                    dst[(((size_t)b * 4 + h) * 2048 + t) * 32 + hd] = f2bf((pa[j][r] + bb) * sc);
                }
            }
        } else {
#pragma unroll
            for (int j = 0; j < 4; j++) {
                const int col = (cb0 + j) * 16 + c2;
                const float bb = ipb[256 + col];
#pragma unroll
                for (int r = 0; r < 4; r++)
                    vls[col][rowblk * 16 + 4 * g + r] = f2bf(pa[j][r] + bb);
            }
        }
    }
    __syncthreads();
    // V^T global write with kappa permutation (PV B-frag = lane's own words)
    {
        const int col = tid >> 1, hf = tid & 1;
        const int h = col >> 5, hd = col & 31;
        const int b = RB >> 11;
        unsigned w[8];
#pragma unroll
        for (int e = 0; e < 8; e++) {
            const int p0 = hf * 16 + 2 * e;
            const int g2 = p0 >> 3, j2 = p0 & 7;
            const int lk = 4 * g2 + j2 + (j2 >= 4 ? 12 : 0);
            w[e] = (unsigned)vls[col][lk] | ((unsigned)vls[col][lk + 1] << 16);
        }
        ushort_t* dst = vo + (((size_t)b * 4 + h) * 32 + hd) * 2048 + (RB & 2047) + hf * 16;
        *(uint4*)dst       = *(const uint4*)&w[0];
        *(uint4*)(dst + 8) = *(const uint4*)&w[4];
    }
}

// ---------------- flash attention: split-K x2, ctx-layout partials -----------
__global__ __launch_bounds__(256) void attn_kernel(
    const ushort_t* __restrict__ q, const ushort_t* __restrict__ k,
    const ushort_t* __restrict__ vtg,
    ushort_t* __restrict__ part, float* __restrict__ rs_part,
    float* __restrict__ m_part)
{
    __shared__ ushort_t ks[2][64][40];   // K tile   [buf][key][hd]
    __shared__ ushort_t vt[2][32][72];   // V^T tile [buf][d][kappa-pos]
    const int tid = threadIdx.x, wid = tid >> 6, lane = tid & 63;
    const int c = lane & 15, g = lane >> 4;
    const int half = blockIdx.x & 1, qt = blockIdx.x >> 1;
    const int bh = blockIdx.y, b = bh >> 2, h = bh & 3;
    const ushort_t* kb_ = k   + (size_t)bh * 65536 + (size_t)half * 1024 * 32;
    const ushort_t* vb_ = vtg + (size_t)bh * 65536 + (size_t)half * 1024;
    const int q0 = qt * 128 + wid * 32;

    const ushort_t* qbase = q + ((size_t)bh * 2048 + q0) * 32;
    const bf16x8 qf0 = *(const bf16x8*)(qbase + (size_t)c * 32 + g * 8);
    const bf16x8 qf1 = *(const bf16x8*)(qbase + (size_t)(16 + c) * 32 + g * 8);

    bf16x8 ones;
#pragma unroll
    for (int i = 0; i < 8; i++) ones[i] = (short)0x3F80;

    float m0 = 0.0f, m1 = 0.0f;
    f32x4 acc[2][2] = {};
    f32x4 racc[2] = {};

    const int srow = tid >> 2, ssg = tid & 3;  // K staging
    const int vd = tid >> 3, vkg = tid & 7;    // V^T staging

    {
        const bf16x8 kk8 = *(const bf16x8*)(kb_ + (size_t)srow * 32 + ssg * 8);
        const bf16x8 vv8 = *(const bf16x8*)(vb_ + (size_t)vd * 2048 + vkg * 8);
        *(bf16x8*)&ks[0][srow][ssg * 8] = kk8;
        *(bf16x8*)&vt[0][vd][vkg * 8] = vv8;
    }
    __syncthreads();

    for (int kt = 0; kt < 16; kt++) {
        const int cur = kt & 1;
        bf16x8 kk8, vv8;
        if (kt + 1 < 16) {
            kk8 = *(const bf16x8*)(kb_ + ((size_t)(kt + 1) * 64 + srow) * 32 + ssg * 8);
            vv8 = *(const bf16x8*)(vb_ + (size_t)vd * 2048 + (kt + 1) * 64 + vkg * 8);
        }

        // ---- QK^T swapped: C[key][q]; kf shared by both Q frags ----
        f32x4 s0[4], s1[4];
#pragma unroll
        for (int kb2 = 0; kb2 < 4; kb2++) {
            const bf16x8 kf = *(const bf16x8*)&ks[cur][kb2 * 16 + c][g * 8];
            f32x4 z = {};
            s0[kb2] = __builtin_amdgcn_mfma_f32_16x16x32_bf16(kf, qf0, z, 0, 0, 0);
            s1[kb2] = __builtin_amdgcn_mfma_f32_16x16x32_bf16(kf, qf1, z, 0, 0, 0);
        }

        // ---- optimistic softmax: p = exp2(s), packed immediately (m==0
        //      fast path); s preserved for the rare exact slow path. ----
        union { unsigned u[4]; bf16x8 v; } p0a, p0b, p1a, p1b;
        p0a.u[0] = cvtpk(exp2f(s0[0][0]), exp2f(s0[0][1]));
        p0a.u[1] = cvtpk(exp2f(s0[0][2]), exp2f(s0[0][3]));
        p0a.u[2] = cvtpk(exp2f(s0[1][0]), exp2f(s0[1][1]));
        p0a.u[3] = cvtpk(exp2f(s0[1][2]), exp2f(s0[1][3]));
        p0b.u[0] = cvtpk(exp2f(s0[2][0]), exp2f(s0[2][1]));
        p0b.u[1] = cvtpk(exp2f(s0[2][2]), exp2f(s0[2][3]));
        p0b.u[2] = cvtpk(exp2f(s0[3][0]), exp2f(s0[3][1]));
        p0b.u[3] = cvtpk(exp2f(s0[3][2]), exp2f(s0[3][3]));
        p1a.u[0] = cvtpk(exp2f(s1[0][0]), exp2f(s1[0][1]));
        p1a.u[1] = cvtpk(exp2f(s1[0][2]), exp2f(s1[0][3]));
        p1a.u[2] = cvtpk(exp2f(s1[1][0]), exp2f(s1[1][1]));
        p1a.u[3] = cvtpk(exp2f(s1[1][2]), exp2f(s1[1][3]));
        p1b.u[0] = cvtpk(exp2f(s1[2][0]), exp2f(s1[2][1]));
        p1b.u[1] = cvtpk(exp2f(s1[2][2]), exp2f(s1[2][3]));
        p1b.u[2] = cvtpk(exp2f(s1[3][0]), exp2f(s1[3][1]));
        p1b.u[3] = cvtpk(exp2f(s1[3][2]), exp2f(s1[3][3]));

        // ---- guard (runs in parallel with the exp2 stream above) ----
        float lm = MX3(s0[0][0], s0[0][1], s0[0][2]);
        lm = MX3(lm, s0[0][3], s0[1][0]);
        lm = MX3(lm, s0[1][1], s0[1][2]);
        lm = MX3(lm, s0[1][3], s0[2][0]);
        lm = MX3(lm, s0[2][1], s0[2][2]);
        lm = MX3(lm, s0[2][3], s0[3][0]);
        lm = MX3(lm, s0[3][1], s0[3][2]);
        lm = MX3(lm, s0[3][3], s1[0][0]);
        lm = MX3(lm, s1[0][1], s1[0][2]);
        lm = MX3(lm, s1[0][3], s1[1][0]);
        lm = MX3(lm, s1[1][1], s1[1][2]);
        lm = MX3(lm, s1[1][3], s1[2][0]);
        lm = MX3(lm, s1[2][1], s1[2][2]);
        lm = MX3(lm, s1[2][3], s1[3][0]);
        lm = MX3(lm, s1[3][1], s1[3][2]);
        lm = fmaxf(lm, s1[3][3]);
        if (__any(lm > 80.0f || m0 != 0.0f || m1 != 0.0f)) {
            // exact online-softmax slow path (rare; s still live)
            float l0 = -1e30f, l1 = -1e30f;
#pragma unroll
            for (int kb2 = 0; kb2 < 4; kb2++) {
#pragma unroll
                for (int r = 0; r < 4; r++) { l0 = fmaxf(l0, s0[kb2][r]); l1 = fmaxf(l1, s1[kb2][r]); }
            }
            l0 = fmaxf(l0, __shfl_xor(l0, 16)); l0 = fmaxf(l0, __shfl_xor(l0, 32));
            l1 = fmaxf(l1, __shfl_xor(l1, 16)); l1 = fmaxf(l1, __shfl_xor(l1, 32));
            const float n0 = fmaxf(m0, l0), n1 = fmaxf(m1, l1);
            const float a0 = exp2f(m0 - n0), a1 = exp2f(m1 - n1);
#pragma unroll
            for (int nb = 0; nb < 2; nb++)
#pragma unroll
                for (int r = 0; r < 4; r++) { acc[0][nb][r] *= a0; acc[1][nb][r] *= a1; }
#pragma unroll
            for (int r = 0; r < 4; r++) { racc[0][r] *= a0; racc[1][r] *= a1; }
            m0 = n0; m1 = n1;
            p0a.u[0] = cvtpk(exp2f(s0[0][0] - m0), exp2f(s0[0][1] - m0));
            p0a.u[1] = cvtpk(exp2f(s0[0][2] - m0), exp2f(s0[0][3] - m0));
            p0a.u[2] = cvtpk(exp2f(s0[1][0] - m0), exp2f(s0[1][1] - m0));
            p0a.u[3] = cvtpk(exp2f(s0[1][2] - m0), exp2f(s0[1][3] - m0));
            p0b.u[0] = cvtpk(exp2f(s0[2][0] - m0), exp2f(s0[2][1] - m0));
            p0b.u[1] = cvtpk(exp2f(s0[2][2] - m0), exp2f(s0[2][3] - m0));
            p0b.u[2] = cvtpk(exp2f(s0[3][0] - m0), exp2f(s0[3][1] - m0));
            p0b.u[3] = cvtpk(exp2f(s0[3][2] - m0), exp2f(s0[3][3] - m0));
            p1a.u[0] = cvtpk(exp2f(s1[0][0] - m1), exp2f(s1[0][1] - m1));
            p1a.u[1] = cvtpk(exp2f(s1[0][2] - m1), exp2f(s1[0][3] - m1));
            p1a.u[2] = cvtpk(exp2f(s1[1][0] - m1), exp2f(s1[1][1] - m1));
            p1a.u[3] = cvtpk(exp2f(s1[1][2] - m1), exp2f(s1[1][3] - m1));
            p1b.u[0] = cvtpk(exp2f(s1[2][0] - m1), exp2f(s1[2][1] - m1));
            p1b.u[1] = cvtpk(exp2f(s1[2][2] - m1), exp2f(s1[2][3] - m1));
            p1b.u[2] = cvtpk(exp2f(s1[3][0] - m1), exp2f(s1[3][1] - m1));
            p1b.u[3] = cvtpk(exp2f(s1[3][2] - m1), exp2f(s1[3][3] - m1));
        }

        // ---- PV + denominator (all on matrix pipe) ----
#pragma unroll
        for (int nb = 0; nb < 2; nb++) {
            const bf16x8 v0 = *(const bf16x8*)&vt[cur][nb * 16 + c][g * 8];
            const bf16x8 v1 = *(const bf16x8*)&vt[cur][nb * 16 + c][32 + g * 8];
            acc[0][nb] = __builtin_amdgcn_mfma_f32_16x16x32_bf16(v0, p0a.v, acc[0][nb], 0, 0, 0);
            acc[0][nb] = __builtin_amdgcn_mfma_f32_16x16x32_bf16(v1, p0b.v, acc[0][nb], 0, 0, 0);
            acc[1][nb] = __builtin_amdgcn_mfma_f32_16x16x32_bf16(v0, p1a.v, acc[1][nb], 0, 0, 0);
            acc[1][nb] = __builtin_amdgcn_mfma_f32_16x16x32_bf16(v1, p1b.v, acc[1][nb], 0, 0, 0);
        }
        racc[0] = __builtin_amdgcn_mfma_f32_16x16x32_bf16(ones, p0a.v, racc[0], 0, 0, 0);
        racc[0] = __builtin_amdgcn_mfma_f32_16x16x32_bf16(ones, p0b.v, racc[0], 0, 0, 0);
        racc[1] = __builtin_amdgcn_mfma_f32_16x16x32_bf16(ones, p1a.v, racc[1], 0, 0, 0);
        racc[1] = __builtin_amdgcn_mfma_f32_16x16x32_bf16(ones, p1b.v, racc[1], 0, 0, 0);

        if (kt + 1 < 16) {
            *(bf16x8*)&ks[cur ^ 1][srow][ssg * 8] = kk8;
            *(bf16x8*)&vt[cur ^ 1][vd][vkg * 8] = vv8;
        }
        __syncthreads();
    }

    // ---- partial store in ctx layout: part[half][b][t][h*32+d] (uint2) ------
    ushort_t* pb = part + (size_t)half * 2097152;
#pragma unroll
    for (int qf = 0; qf < 2; qf++) {
        const int qrow = q0 + qf * 16 + c;
        ushort_t* dst = pb + ((size_t)(b * 2048 + qrow)) * 128 + h * 32;
#pragma unroll
        for (int nb = 0; nb < 2; nb++) {
            uint2 wv;
            wv.x = cvtpk(acc[qf][nb][0], acc[qf][nb][1]);
            wv.y = cvtpk(acc[qf][nb][2], acc[qf][nb][3]);
            *(uint2*)(dst + nb * 16 + 4 * g) = wv;
        }
    }
    if (g == 0) {
        float* rsp = rs_part + (size_t)(half * 32 + bh) * 2048;
        float* mp  = m_part  + (size_t)(half * 32 + bh) * 2048;
        rsp[q0 + c]      = racc[0][0];
        rsp[q0 + 16 + c] = racc[1][0];
        mp[q0 + c]       = m0;
        mp[q0 + 16 + c]  = m1;
    }
}

// ------- fused split-K combine + out-proj + residual-LN + final GEMM ---------
__global__ __launch_bounds__(256) void out_fuse(
    const ushort_t* __restrict__ ctxA, const ushort_t* __restrict__ ctxB,
    const float* __restrict__ rs_part, const float* __restrict__ m_part,
    const ushort_t* __restrict__ treb,
    const ushort_t* __restrict__ opw, const float* __restrict__ opb,
    const float* __restrict__ cn_g, const float* __restrict__ cn_b,
    const ushort_t* __restrict__ ofw, const float* __restrict__ of_b,
    const float* __restrict__ of_g, const float* __restrict__ of_beta,
    const ushort_t* __restrict__ lobe_b, float* __restrict__ out)
{
    __shared__ ushort_t fus_t[32][136];
    __shared__ float red[32][2][2];
    const int tid = threadIdx.x, wid = tid >> 6, lane = tid & 63;
    const int c2 = lane & 15, g = lane >> 4;
    const int rowblk = wid >> 1, chf = wid & 1, cb0 = chf * 4;
    const int RB = blockIdx.x * 32;
    const int R0 = RB + rowblk * 16;

    // ---- per-lane-row, per-head combine factors ----
    const int rowA = R0 + c2;
    const int bb2 = rowA >> 11, tt = rowA & 2047;
    float fA[4], fB[4];
#pragma unroll
    for (int h = 0; h < 4; h++) {
        const int bh = bb2 * 4 + h;
        const float mA = m_part[(size_t)bh * 2048 + tt];
        const float mB = m_part[(size_t)(32 + bh) * 2048 + tt];
        const float rA = rs_part[(size_t)bh * 2048 + tt];
        const float rB = rs_part[(size_t)(32 + bh) * 2048 + tt];
        const float M = fmaxf(mA, mB);
        const float wA = exp2f(mA - M), wB = exp2f(mB - M);
        const float inv = __builtin_amdgcn_rcpf(fmaf(rA, wA, rB * wB));
        fA[h] = wA * inv; fB[h] = wB * inv;
    }

    // ---- phase A: fused = LN(lobe + combined_ctx @ opw + opb) ----
    f32x4 acc[4] = {};
#pragma unroll
    for (int ch = 0; ch < 4; ch++) {
        const bf16x8 aA = *(const bf16x8*)(ctxA + (size_t)rowA * 128 + ch * 32 + g * 8);
        const bf16x8 aB = *(const bf16x8*)(ctxB + (size_t)rowA * 128 + ch * 32 + g * 8);
        union { unsigned u[4]; bf16x8 v; } am;
#pragma unroll
        for (int i = 0; i < 4; i++) {
            const float e0 = bf2f((ushort_t)aA[2 * i]) * fA[ch] + bf2f((ushort_t)aB[2 * i]) * fB[ch];
            const float e1 = bf2f((ushort_t)aA[2 * i + 1]) * fA[ch] + bf2f((ushort_t)aB[2 * i + 1]) * fB[ch];
            am.u[i] = cvtpk(e0, e1);
        }
#pragma unroll
        for (int j = 0; j < 4; j++) {
            const bf16x8 b = *(const bf16x8*)(opw + (size_t)((cb0 + j) * 16 + c2) * 128 + ch * 32 + g * 8);
            acc[j] = __builtin_amdgcn_mfma_f32_16x16x32_bf16(am.v, b, acc[j], 0, 0, 0);
        }
    }
#pragma unroll
    for (int j = 0; j < 4; j++) {
        const int col = (cb0 + j) * 16 + c2;
        const float bb = opb[col];
#pragma unroll
        for (int r = 0; r < 4; r++)
            acc[j][r] += bb + bf2f(lobe_b[(size_t)(R0 + 4 * g + r) * 128 + col]);
    }
#pragma unroll
    for (int r = 0; r < 4; r++) {
        float s = 0.f, ss = 0.f;
#pragma unroll
        for (int j = 0; j < 4; j++) { const float v = acc[j][r]; s += v; ss = fmaf(v, v, ss); }
#pragma unroll
        for (int o = 8; o; o >>= 1) { s += __shfl_xor(s, o); ss += __shfl_xor(ss, o); }
        if (c2 == 0) {
            red[rowblk * 16 + 4 * g + r][chf][0] = s;
            red[rowblk * 16 + 4 * g + r][chf][1] = ss;
        }
    }
    __syncthreads();
#pragma unroll
    for (int r = 0; r < 4; r++) {
        const int lr = rowblk * 16 + 4 * g + r;
        const float S  = red[lr][0][0] + red[lr][1][0];
        const float SS = red[lr][0][1] + red[lr][1][1];
        const float mean = S * (1.0f / 128.0f);
        const float rstd = rsqrtf(fmaxf(SS * (1.0f / 128.0f) - mean * mean, 0.0f) + 1e-5f);
#pragma unroll
        for (int j = 0; j < 4; j++) {
            const int col = (cb0 + j) * 16 + c2;
            fus_t[lr][col] = f2bf((acc[j][r] - mean) * rstd * cn_g[col] + cn_b[col]);
        }
    }
    __syncthreads();

    // ---- phase B: out = gelu(LN([fused, tre]@ofw + ofb)) ----
    f32x4 a2[4] = {};
#pragma unroll
    for (int ch = 0; ch < 8; ch++) {
        bf16x8 a;
        if (ch < 4) a = *(const bf16x8*)&fus_t[rowblk * 16 + c2][ch * 32 + g * 8];
        else        a = *(const bf16x8*)(treb + (size_t)(R0 + c2) * 128 + (ch - 4) * 32 + g * 8);
#pragma unroll
        for (int j = 0; j < 4; j++) {
            const bf16x8 b = *(const bf16x8*)(ofw + (size_t)((cb0 + j) * 16 + c2) * 256 + ch * 32 + g * 8);
            a2[j] = __builtin_amdgcn_mfma_f32_16x16x32_bf16(a, b, a2[j], 0, 0, 0);
        }
    }
#pragma unroll
    for (int j = 0; j < 4; j++) {
        const float bb = of_b[(cb0 + j) * 16 + c2];
#pragma unroll
        for (int r = 0; r < 4; r++) a2[j][r] += bb;
    }
#pragma unroll
    for (int r = 0; r < 4; r++) {
        float s = 0.f, ss = 0.f;
#pragma unroll
        for (int j = 0; j < 4; j++) { const float v = a2[j][r]; s += v; ss = fmaf(v, v, ss); }
#pragma unroll
        for (int o = 8; o; o >>= 1) { s += __shfl_xor(s, o); ss += __shfl_xor(ss, o); }
        if (c2 == 0) {
            red[rowblk * 16 + 4 * g + r][chf][0] = s;
            red[rowblk * 16 + 4 * g + r][chf][1] = ss;
        }
    }
    __syncthreads();
#pragma unroll
    for (int r = 0; r < 4; r++) {
        const int lr = rowblk * 16 + 4 * g + r;
        const float S  = red[lr][0][0] + red[lr][1][0];
        const float SS = red[lr][0][1] + red[lr][1][1];
        const float mean = S * (1.0f / 128.0f);
        const float rstd = rsqrtf(fmaxf(SS * (1.0f / 128.0f) - mean * mean, 0.0f) + 1e-5f);
        const int R = RB + lr;
#pragma unroll
        for (int j = 0; j < 4; j++) {
            const int col = (cb0 + j) * 16 + c2;
            const float y = (a2[j][r] - mean) * rstd * of_g[col] + of_beta[col];
            out[(size_t)R * 128 + col] = gelu_f(y);
        }
    }
}

// ---------------- decay scan: carry -> re-scan -------------------------------
__global__ void scan_carry_kernel(const float* __restrict__ ends,
                                  const float* __restrict__ decay,
                                  float* __restrict__ carry)
{
    const int c = threadIdx.x;
    const int b = blockIdx.x;
    const float d = sigm(decay[c]);
    float dl = d;
#pragma unroll
    for (int i = 0; i < 6; i++) dl *= dl;  // d^64
    float e = 0.0f;
#pragma unroll
    for (int ch = 0; ch < 32; ch++) {
        carry[((size_t)b * 32 + ch) * 128 + c] = e;
        e = fmaf(dl, e, ends[((size_t)b * 32 + ch) * 128 + c]);
    }
}

__global__ void scan_fin_kernel(const ushort_t* __restrict__ imp,
                                const float* __restrict__ decay,
                                const float* __restrict__ carry,
                                ushort_t* __restrict__ stbf)
{
    const int c = threadIdx.x;
    const int ch = blockIdx.x, b = blockIdx.y;
    const float d = sigm(decay[c]);
    float s = carry[((size_t)b * 32 + ch) * 128 + c];
    const size_t base = ((size_t)b * T_ + ch * 64) * 128 + c;
#pragma unroll 4
    for (int tl = 0; tl < 64; tl++) {
        s = fmaf(d, s, bf2f(imp[base + (size_t)tl * 128]));
        stbf[base + (size_t)tl * 128] = f2bf(s);
    }
}

extern "C" void kernel_launch(void* const* d_in, const int* in_sizes, int n_in,
                              void* d_out, int out_size, void* d_ws, size_t ws_size,
                              hipStream_t stream)
{
    const float* lob_feat   = (const float*)d_in[0];
    const float* trade_feat = (const float*)d_in[1];
    const float* has_trade  = (const float*)d_in[2];
    const float* ei_w       = (const float*)d_in[3];
    const float* ei_b       = (const float*)d_in[4];
    const float* ei_g       = (const float*)d_in[5];
    const float* ei_beta    = (const float*)d_in[6];
    const float* decay      = (const float*)d_in[7];
    const float* in_proj_w  = (const float*)d_in[8];
    const float* in_proj_b  = (const float*)d_in[9];
    const float* out_proj_w = (const float*)d_in[10];
    const float* out_proj_b = (const float*)d_in[11];
    const float* cn_g       = (const float*)d_in[12];
    const float* cn_b       = (const float*)d_in[13];
    const float* lob_w      = (const float*)d_in[14];
    const float* lob_b      = (const float*)d_in[15];
    const float* lob_g      = (const float*)d_in[16];
    const float* lob_beta   = (const float*)d_in[17];
    const float* tr_w       = (const float*)d_in[18];
    const float* tr_b       = (const float*)d_in[19];
    const float* tr_g       = (const float*)d_in[20];
    const float* tr_beta    = (const float*)d_in[21];
    const float* of_w       = (const float*)d_in[22];
    const float* of_b       = (const float*)d_in[23];
    const float* of_g       = (const float*)d_in[24];
    const float* of_beta    = (const float*)d_in[25];

    char* W = (char*)d_ws;
    const size_t MB = 1u << 20;
    ushort_t* lobe_b   = (ushort_t*)W;               // 0-4 MB
    float*    carry    = (float*)(W + 8 * MB);
    float*    ends     = (float*)(W + 8 * MB + 256 * 1024);
    ushort_t* pool     = (ushort_t*)(W + 9 * MB);    // 9-9.4 MB (weights only)
    ushort_t* imp_bf   = (ushort_t*)(W + 18 * MB);   // 18-22
    ushort_t* state_bf = (ushort_t*)(W + 22 * MB);
    ushort_t* tre_bf   = (ushort_t*)(W + 26 * MB);
    ushort_t* q_bf     = (ushort_t*)(W + 30 * MB);
    ushort_t* k_bf     = (ushort_t*)(W + 34 * MB);
    ushort_t* vt_g     = (ushort_t*)(W + 38 * MB);
    ushort_t* part     = (ushort_t*)(W + 42 * MB);   // 2 x 4 MB ctx partials
    float*    rs_part  = (float*)(W + 50 * MB);      // 512 KB
    float*    m_part   = (float*)(W + 50 * MB + 512 * 1024);

    ushort_t* eiw_bf   = pool;
    ushort_t* ipw_bf   = pool + 16384;
    ushort_t* opw_bf   = pool + 65536;
    ushort_t* lobw_bf  = pool + 81920;
    ushort_t* trw_bf   = pool + 114688;
    ushort_t* ofw_bf   = pool + 147456;

    ushort_t* ctxA = part;
    ushort_t* ctxB = part + 2097152;

    const dim3 blk(256);

    prep_w<<<dim3(88), blk, 0, stream>>>(ei_w, in_proj_w, out_proj_w, lob_w, tr_w, of_w, pool);
    ei_scan<<<dim3(256), dim3(512), 0, stream>>>(trade_feat, eiw_bf, ei_b, ei_g, ei_beta,
                                                 has_trade, decay, imp_bf, ends);
    scan_carry_kernel<<<dim3(8), dim3(128), 0, stream>>>(ends, decay, carry);
    scan_fin_kernel<<<dim3(32, 8), dim3(128), 0, stream>>>(imp_bf, decay, carry, state_bf);
    enh_qkv<<<dim3(512), blk, 0, stream>>>(lob_feat, trade_feat, state_bf, lobw_bf, trw_bf,
                                           ipw_bf, in_proj_b, lob_b, lob_g, lob_beta,
                                           tr_b, tr_g, tr_beta, lobe_b, tre_bf,
                                           q_bf, k_bf, vt_g);
    attn_kernel<<<dim3(32, 32), blk, 0, stream>>>(q_bf, k_bf, vt_g, part, rs_part, m_part);
    out_fuse<<<dim3(512), blk, 0, stream>>>(ctxA, ctxB, rs_part, m_part, tre_bf,
                                            opw_bf, out_proj_b, cn_g, cn_b,
                                            ofw_bf, of_b, of_g, of_beta, lobe_b, (float*)d_out);
}